// Round 1
// baseline (962.413 us; speedup 1.0000x reference)
//
#include <hip/hip_runtime.h>
#include <stdint.h>

// ---------------- threefry2x32 (JAX-compatible, 20 rounds) ----------------
#define TF_ROUND(x0, x1, r)                                                    \
  {                                                                            \
    x0 += x1;                                                                  \
    x1 = (x1 << r) | (x1 >> (32 - r));                                         \
    x1 ^= x0;                                                                  \
  }

__host__ __device__ inline void threefry2x32(uint32_t k0, uint32_t k1,
                                             uint32_t x0, uint32_t x1,
                                             uint32_t* o0, uint32_t* o1) {
  uint32_t ks2 = k0 ^ k1 ^ 0x1BD11BDAu;
  x0 += k0; x1 += k1;
  TF_ROUND(x0, x1, 13) TF_ROUND(x0, x1, 15) TF_ROUND(x0, x1, 26) TF_ROUND(x0, x1, 6)
  x0 += k1; x1 += ks2 + 1u;
  TF_ROUND(x0, x1, 17) TF_ROUND(x0, x1, 29) TF_ROUND(x0, x1, 16) TF_ROUND(x0, x1, 24)
  x0 += ks2; x1 += k0 + 2u;
  TF_ROUND(x0, x1, 13) TF_ROUND(x0, x1, 15) TF_ROUND(x0, x1, 26) TF_ROUND(x0, x1, 6)
  x0 += k0; x1 += k1 + 3u;
  TF_ROUND(x0, x1, 17) TF_ROUND(x0, x1, 29) TF_ROUND(x0, x1, 16) TF_ROUND(x0, x1, 24)
  x0 += k1; x1 += ks2 + 4u;
  TF_ROUND(x0, x1, 13) TF_ROUND(x0, x1, 15) TF_ROUND(x0, x1, 26) TF_ROUND(x0, x1, 6)
  x0 += ks2; x1 += k0 + 5u;
  *o0 = x0; *o1 = x1;
}

// partitionable random_bits for 32-bit: bits(j) = o0 ^ o1 of threefry(key, (0, j))
__device__ inline uint32_t tf_bits32(uint32_t k0, uint32_t k1, uint32_t ctr) {
  uint32_t a, b;
  threefry2x32(k0, k1, 0u, ctr, &a, &b);
  return a ^ b;
}

// ---------------- degree / normalization ----------------
__global__ void k_init_one(float* __restrict__ dis, int n) {
  int i = blockIdx.x * blockDim.x + threadIdx.x;
  if (i < n) dis[i] = 1.0f;  // self-loop contribution to degree
}

__global__ void k_deg(const int* __restrict__ dst, float* __restrict__ dis, int E) {
  int t = blockIdx.x * blockDim.x + threadIdx.x;
  int stride = gridDim.x * blockDim.x;
  for (int e = t; e < E; e += stride) atomicAdd(&dis[dst[e]], 1.0f);
}

__global__ void k_rsqrt(float* __restrict__ dis, int n) {
  int i = blockIdx.x * blockDim.x + threadIdx.x;
  if (i < n) dis[i] = rsqrtf(dis[i]);  // deg >= 1 always (self-loops)
}

// ---------------- GEMM1: h1[n,128] = x[n,128] @ W[128,128] ----------------
__global__ __launch_bounds__(256) void k_gemm1(const float* __restrict__ x,
                                               const float* __restrict__ W,
                                               float* __restrict__ h, int n) {
  __shared__ float xs[64][128];
  const int rowBase = blockIdx.x * 64;
  for (int i = threadIdx.x; i < 64 * 32; i += 256) {
    int r = i >> 5, c4 = i & 31;
    float4 v = make_float4(0.f, 0.f, 0.f, 0.f);
    if (rowBase + r < n)
      v = ((const float4*)(x + (size_t)(rowBase + r) * 128))[c4];
    *(float4*)&xs[r][c4 * 4] = v;
  }
  __syncthreads();
  const int tc = threadIdx.x & 31;  // cols tc*4 .. tc*4+3
  const int tr = threadIdx.x >> 5;  // rows tr*8 .. tr*8+7
  float acc[8][4];
#pragma unroll
  for (int r = 0; r < 8; ++r)
#pragma unroll
    for (int c = 0; c < 4; ++c) acc[r][c] = 0.f;
#pragma unroll 4
  for (int k = 0; k < 128; ++k) {
    const float4 wv = *(const float4*)&W[k * 128 + tc * 4];
    float xr[8];
#pragma unroll
    for (int r = 0; r < 8; ++r) xr[r] = xs[tr * 8 + r][k];
#pragma unroll
    for (int r = 0; r < 8; ++r) {
      acc[r][0] += xr[r] * wv.x;
      acc[r][1] += xr[r] * wv.y;
      acc[r][2] += xr[r] * wv.z;
      acc[r][3] += xr[r] * wv.w;
    }
  }
#pragma unroll
  for (int r = 0; r < 8; ++r) {
    int row = rowBase + tr * 8 + r;
    if (row < n)
      *(float4*)&h[(size_t)row * 128 + tc * 4] =
          make_float4(acc[r][0], acc[r][1], acc[r][2], acc[r][3]);
  }
}

// ---------------- self-loop init: agg = h * dis[v]^2 ----------------
__global__ void k_selfinit(const float4* __restrict__ hsrc,
                           const float* __restrict__ dis,
                           float4* __restrict__ agg, int total, int qshift) {
  int i = blockIdx.x * blockDim.x + threadIdx.x;
  if (i >= total) return;
  int v = i >> qshift;
  float w = dis[v];
  w = w * w;
  float4 t = hsrc[i];
  t.x *= w; t.y *= w; t.z *= w; t.w *= w;
  agg[i] = t;
}

// ---------------- edge scatter, 128 feats: one wave per edge ----------------
__global__ void k_scatter1(const int* __restrict__ src, const int* __restrict__ dst,
                           const float* __restrict__ dis, const float* __restrict__ h1,
                           float* __restrict__ agg, int E) {
  int lane = threadIdx.x & 63;
  int wid = (blockIdx.x * blockDim.x + threadIdx.x) >> 6;
  int nw = (gridDim.x * blockDim.x) >> 6;
  for (int e = wid; e < E; e += nw) {
    int s = src[e], d = dst[e];
    float w = dis[s] * dis[d];
    float v0 = h1[(size_t)s * 128 + lane] * w;
    float v1 = h1[(size_t)s * 128 + 64 + lane] * w;
    atomicAdd(&agg[(size_t)d * 128 + lane], v0);
    atomicAdd(&agg[(size_t)d * 128 + 64 + lane], v1);
  }
}

// ---------------- edge scatter, 16 feats: 16 lanes per edge ----------------
__global__ void k_scatter2(const int* __restrict__ src, const int* __restrict__ dst,
                           const float* __restrict__ dis, const float* __restrict__ h2,
                           float* __restrict__ agg, int E) {
  int t = blockIdx.x * blockDim.x + threadIdx.x;
  int stride = gridDim.x * blockDim.x;
  int total = E * 16;
  for (int i = t; i < total; i += stride) {
    int e = i >> 4, k = i & 15;
    int s = src[e], d = dst[e];
    float w = dis[s] * dis[d];
    atomicAdd(&agg[(size_t)d * 16 + k], h2[(size_t)s * 16 + k] * w);
  }
}

// ---------------- bias + PReLU + dropout (in-place) ----------------
__global__ void k_post(const float* __restrict__ bias, const float* __restrict__ pa,
                       float* __restrict__ buf, int total, int cmask,
                       uint32_t k0, uint32_t k1) {
  int j = blockIdx.x * blockDim.x + threadIdx.x;
  if (j >= total) return;
  float v = buf[j] + bias[j & cmask];
  float a = pa[0];
  v = v >= 0.f ? v : a * v;
  uint32_t bits = tf_bits32(k0, k1, (uint32_t)j);
  // keep iff uniform < 0.5 iff bits < 2^31; kept values scaled by 1/(1-p)=2
  buf[j] = (bits & 0x80000000u) ? 0.f : 2.f * v;
}

// ---------------- GEMM2: h2[n,16] = h[n,128] @ W2[128,16] ----------------
__global__ __launch_bounds__(256) void k_gemm2(const float* __restrict__ hin,
                                               const float* __restrict__ W2,
                                               float* __restrict__ h2, int n) {
  __shared__ float xs[64][132];
  const int rowBase = blockIdx.x * 64;
  for (int i = threadIdx.x; i < 64 * 32; i += 256) {
    int r = i >> 5, c4 = i & 31;
    float4 v = make_float4(0.f, 0.f, 0.f, 0.f);
    if (rowBase + r < n)
      v = ((const float4*)(hin + (size_t)(rowBase + r) * 128))[c4];
    *(float4*)&xs[r][c4 * 4] = v;
  }
  __syncthreads();
  const int r = threadIdx.x >> 2;
  const int cg = threadIdx.x & 3;
  float acc[4] = {0.f, 0.f, 0.f, 0.f};
#pragma unroll 4
  for (int k = 0; k < 128; ++k) {
    float xv = xs[r][k];
    const float4 wv = *(const float4*)&W2[k * 16 + cg * 4];
    acc[0] += xv * wv.x;
    acc[1] += xv * wv.y;
    acc[2] += xv * wv.z;
    acc[3] += xv * wv.w;
  }
  int row = rowBase + r;
  if (row < n)
    *(float4*)&h2[(size_t)row * 16 + cg * 4] =
        make_float4(acc[0], acc[1], acc[2], acc[3]);
}

// ---------------- GEMM3: out[n,10] = hp[n,16] @ Wfc[16,10] + bfc ----------------
__global__ void k_gemm3(const float* __restrict__ hp, const float* __restrict__ Wfc,
                        const float* __restrict__ bfc, float* __restrict__ out, int n) {
  int row = blockIdx.x * blockDim.x + threadIdx.x;
  if (row >= n) return;
  float hrow[16];
#pragma unroll
  for (int q = 0; q < 4; ++q) {
    float4 v = ((const float4*)(hp + (size_t)row * 16))[q];
    hrow[q * 4 + 0] = v.x; hrow[q * 4 + 1] = v.y;
    hrow[q * 4 + 2] = v.z; hrow[q * 4 + 3] = v.w;
  }
#pragma unroll
  for (int c = 0; c < 10; ++c) {
    float acc = bfc[c];
#pragma unroll
    for (int k = 0; k < 16; ++k) acc += hrow[k] * Wfc[k * 10 + c];
    out[(size_t)row * 10 + c] = acc;
  }
}

extern "C" void kernel_launch(void* const* d_in, const int* in_sizes, int n_in,
                              void* d_out, int out_size, void* d_ws, size_t ws_size,
                              hipStream_t stream) {
  const float* x   = (const float*)d_in[0];
  const int*   ei  = (const int*)d_in[1];
  const float* W1  = (const float*)d_in[2];
  const float* b1  = (const float*)d_in[3];
  const float* W2  = (const float*)d_in[4];
  const float* b2  = (const float*)d_in[5];
  const float* pa  = (const float*)d_in[6];
  const float* Wfc = (const float*)d_in[7];
  const float* bfc = (const float*)d_in[8];
  float* out = (float*)d_out;

  const int n = in_sizes[0] / 128;
  const int E = in_sizes[1] / 2;
  const int* src = ei;
  const int* dst = ei + E;

  float* ws   = (float*)d_ws;
  float* dis  = ws;                         // n
  float* bufA = ws + n;                     // n*128: h1, later h2+agg2
  float* bufB = bufA + (size_t)n * 128;     // n*128: agg1 -> h
  float* h2   = bufA;                       // n*16
  float* agg2 = bufA + (size_t)n * 16;      // n*16

  // ---- host-side JAX key derivation (partitionable threefry) ----
  // dk1, dk2 = split(key(42)); key(42) -> (0, 42)
  uint32_t dk1_0, dk1_1, dk2_0, dk2_1;
  threefry2x32(0u, 42u, 0u, 0u, &dk1_0, &dk1_1);  // counter 0 -> dk1
  threefry2x32(0u, 42u, 0u, 1u, &dk2_0, &dk2_1);  // counter 1 -> dk2

  // 1. degree -> dis
  k_init_one<<<(n + 255) / 256, 256, 0, stream>>>(dis, n);
  k_deg<<<2048, 256, 0, stream>>>(dst, dis, E);
  k_rsqrt<<<(n + 255) / 256, 256, 0, stream>>>(dis, n);

  // 2. h1 = x @ W1
  k_gemm1<<<(n + 63) / 64, 256, 0, stream>>>(x, W1, bufA, n);

  // 3. aggregate layer 1: agg1 = self-loop + edges
  k_selfinit<<<(n * 32 + 255) / 256, 256, 0, stream>>>(
      (const float4*)bufA, dis, (float4*)bufB, n * 32, 5);
  k_scatter1<<<4096, 256, 0, stream>>>(src, dst, dis, bufA, bufB, E);

  // 4. h = dropout(prelu(agg1 + b1)) with dk1
  k_post<<<(n * 128 + 255) / 256, 256, 0, stream>>>(b1, pa, bufB, n * 128, 127,
                                                    dk1_0, dk1_1);

  // 5. h2 = h @ W2
  k_gemm2<<<(n + 63) / 64, 256, 0, stream>>>(bufB, W2, h2, n);

  // 6. aggregate layer 2
  k_selfinit<<<(n * 4 + 255) / 256, 256, 0, stream>>>(
      (const float4*)h2, dis, (float4*)agg2, n * 4, 2);
  k_scatter2<<<4096, 256, 0, stream>>>(src, dst, dis, h2, agg2, E);

  // 7. dropout(prelu(agg2 + b2)) with dk2
  k_post<<<(n * 16 + 255) / 256, 256, 0, stream>>>(b2, pa, agg2, n * 16, 15,
                                                   dk2_0, dk2_1);

  // 8. out = hp @ Wfc + bfc
  k_gemm3<<<(n + 255) / 256, 256, 0, stream>>>(agg2, Wfc, bfc, out, n);
}

// Round 2
// 558.068 us; speedup vs baseline: 1.7245x; 1.7245x over previous
//
#include <hip/hip_runtime.h>
#include <stdint.h>

// ---------------- threefry2x32 (JAX-compatible, 20 rounds) ----------------
#define TF_ROUND(x0, x1, r)                                                    \
  {                                                                            \
    x0 += x1;                                                                  \
    x1 = (x1 << r) | (x1 >> (32 - r));                                         \
    x1 ^= x0;                                                                  \
  }

__host__ __device__ inline void threefry2x32(uint32_t k0, uint32_t k1,
                                             uint32_t x0, uint32_t x1,
                                             uint32_t* o0, uint32_t* o1) {
  uint32_t ks2 = k0 ^ k1 ^ 0x1BD11BDAu;
  x0 += k0; x1 += k1;
  TF_ROUND(x0, x1, 13) TF_ROUND(x0, x1, 15) TF_ROUND(x0, x1, 26) TF_ROUND(x0, x1, 6)
  x0 += k1; x1 += ks2 + 1u;
  TF_ROUND(x0, x1, 17) TF_ROUND(x0, x1, 29) TF_ROUND(x0, x1, 16) TF_ROUND(x0, x1, 24)
  x0 += ks2; x1 += k0 + 2u;
  TF_ROUND(x0, x1, 13) TF_ROUND(x0, x1, 15) TF_ROUND(x0, x1, 26) TF_ROUND(x0, x1, 6)
  x0 += k0; x1 += k1 + 3u;
  TF_ROUND(x0, x1, 17) TF_ROUND(x0, x1, 29) TF_ROUND(x0, x1, 16) TF_ROUND(x0, x1, 24)
  x0 += k1; x1 += ks2 + 4u;
  TF_ROUND(x0, x1, 13) TF_ROUND(x0, x1, 15) TF_ROUND(x0, x1, 26) TF_ROUND(x0, x1, 6)
  x0 += ks2; x1 += k0 + 5u;
  *o0 = x0; *o1 = x1;
}

__device__ inline uint32_t tf_bits32(uint32_t k0, uint32_t k1, uint32_t ctr) {
  uint32_t a, b;
  threefry2x32(k0, k1, 0u, ctr, &a, &b);
  return a ^ b;
}

// ---------------- degree ----------------
__global__ void k_init_one(float* __restrict__ dis, int n) {
  int i = blockIdx.x * blockDim.x + threadIdx.x;
  if (i < n) dis[i] = 1.0f;  // self-loop contribution
}

__global__ void k_deg(const int* __restrict__ dst, float* __restrict__ dis, int E) {
  int t = blockIdx.x * blockDim.x + threadIdx.x;
  int stride = gridDim.x * blockDim.x;
  for (int e = t; e < E; e += stride) atomicAdd(&dis[dst[e]], 1.0f);
}

__global__ void k_rsqrt(float* __restrict__ dis, int n) {
  int i = blockIdx.x * blockDim.x + threadIdx.x;
  if (i < n) dis[i] = rsqrtf(dis[i]);
}

// ---------------- CSR build: exclusive scan of (deg-1) ----------------
#define SCAN_CHUNK 1024

__global__ __launch_bounds__(256) void k_blocksum(const float* __restrict__ deg,
                                                  int n, int* __restrict__ bs) {
  __shared__ int sdata[256];
  int base = blockIdx.x * SCAN_CHUNK;
  int s = 0;
  for (int i = threadIdx.x; i < SCAN_CHUNK; i += 256) {
    int idx = base + i;
    if (idx < n) s += (int)deg[idx] - 1;
  }
  sdata[threadIdx.x] = s;
  __syncthreads();
  for (int off = 128; off > 0; off >>= 1) {
    if (threadIdx.x < off) sdata[threadIdx.x] += sdata[threadIdx.x + off];
    __syncthreads();
  }
  if (threadIdx.x == 0) bs[blockIdx.x] = sdata[0];
}

__global__ __launch_bounds__(256) void k_scanbs(int* __restrict__ bs, int G) {
  __shared__ int sh[256];
  int v = (threadIdx.x < G) ? bs[threadIdx.x] : 0;
  sh[threadIdx.x] = v;
  __syncthreads();
  for (int off = 1; off < 256; off <<= 1) {
    int t = (threadIdx.x >= off) ? sh[threadIdx.x - off] : 0;
    __syncthreads();
    sh[threadIdx.x] += t;
    __syncthreads();
  }
  if (threadIdx.x < G) bs[threadIdx.x] = sh[threadIdx.x] - v;  // exclusive
}

__global__ __launch_bounds__(256) void k_scanfinal(const float* __restrict__ deg,
                                                   int n, const int* __restrict__ bs,
                                                   int* __restrict__ rowptr,
                                                   int* __restrict__ cursor, int E) {
  __shared__ int sh[256];
  int base = blockIdx.x * SCAN_CHUNK;
  int idx0 = base + threadIdx.x * 4;
  int c[4];
  int local = 0;
#pragma unroll
  for (int q = 0; q < 4; ++q) {
    int idx = idx0 + q;
    c[q] = (idx < n) ? (int)deg[idx] - 1 : 0;
    local += c[q];
  }
  sh[threadIdx.x] = local;
  __syncthreads();
  for (int off = 1; off < 256; off <<= 1) {
    int t = (threadIdx.x >= off) ? sh[threadIdx.x - off] : 0;
    __syncthreads();
    sh[threadIdx.x] += t;
    __syncthreads();
  }
  int pre = bs[blockIdx.x] + sh[threadIdx.x] - local;  // exclusive prefix
#pragma unroll
  for (int q = 0; q < 4; ++q) {
    int idx = idx0 + q;
    if (idx < n) { rowptr[idx] = pre; cursor[idx] = pre; }
    pre += c[q];
  }
  if (blockIdx.x == 0 && threadIdx.x == 0) rowptr[n] = E;
}

__global__ void k_fill(const int* __restrict__ src, const int* __restrict__ dst,
                       int* __restrict__ cursor, int* __restrict__ csrc, int E) {
  int t = blockIdx.x * blockDim.x + threadIdx.x;
  int stride = gridDim.x * blockDim.x;
  for (int e = t; e < E; e += stride) {
    int slot = atomicAdd(&cursor[dst[e]], 1);
    csrc[slot] = src[e];
  }
}

// ---------------- GEMM1: h1[n,128] = x[n,128] @ W[128,128] ----------------
__global__ __launch_bounds__(256) void k_gemm1(const float* __restrict__ x,
                                               const float* __restrict__ W,
                                               float* __restrict__ h, int n) {
  __shared__ float xs[64][128];
  const int rowBase = blockIdx.x * 64;
  for (int i = threadIdx.x; i < 64 * 32; i += 256) {
    int r = i >> 5, c4 = i & 31;
    float4 v = make_float4(0.f, 0.f, 0.f, 0.f);
    if (rowBase + r < n)
      v = ((const float4*)(x + (size_t)(rowBase + r) * 128))[c4];
    *(float4*)&xs[r][c4 * 4] = v;
  }
  __syncthreads();
  const int tc = threadIdx.x & 31;
  const int tr = threadIdx.x >> 5;
  float acc[8][4];
#pragma unroll
  for (int r = 0; r < 8; ++r)
#pragma unroll
    for (int c = 0; c < 4; ++c) acc[r][c] = 0.f;
#pragma unroll 4
  for (int k = 0; k < 128; ++k) {
    const float4 wv = *(const float4*)&W[k * 128 + tc * 4];
    float xr[8];
#pragma unroll
    for (int r = 0; r < 8; ++r) xr[r] = xs[tr * 8 + r][k];
#pragma unroll
    for (int r = 0; r < 8; ++r) {
      acc[r][0] += xr[r] * wv.x;
      acc[r][1] += xr[r] * wv.y;
      acc[r][2] += xr[r] * wv.z;
      acc[r][3] += xr[r] * wv.w;
    }
  }
#pragma unroll
  for (int r = 0; r < 8; ++r) {
    int row = rowBase + tr * 8 + r;
    if (row < n)
      *(float4*)&h[(size_t)row * 128 + tc * 4] =
          make_float4(acc[r][0], acc[r][1], acc[r][2], acc[r][3]);
  }
}

// ---- gather layer 1 (one wave per node) + bias + prelu + dropout fused ----
__global__ void k_gather1(const int* __restrict__ rowptr, const int* __restrict__ csrc,
                          const float* __restrict__ dis, const float* __restrict__ h1,
                          const float* __restrict__ bias, const float* __restrict__ pa,
                          float* __restrict__ outbuf, int n, uint32_t k0, uint32_t k1) {
  int lane = threadIdx.x & 63;
  int v = (blockIdx.x * blockDim.x + threadIdx.x) >> 6;
  if (v >= n) return;
  float dv = dis[v];
  float2 self = ((const float2*)(h1 + (size_t)v * 128))[lane];
  float2 acc = make_float2(self.x * dv * dv, self.y * dv * dv);
  int beg = rowptr[v], end = rowptr[v + 1];
  for (int j = beg; j < end; ++j) {
    int s = csrc[j];
    float w = dis[s] * dv;
    float2 hv = ((const float2*)(h1 + (size_t)s * 128))[lane];
    acc.x += hv.x * w;
    acc.y += hv.y * w;
  }
  float a = pa[0];
  int f0 = lane * 2;
  float v0 = acc.x + bias[f0];
  float v1 = acc.y + bias[f0 + 1];
  v0 = v0 >= 0.f ? v0 : a * v0;
  v1 = v1 >= 0.f ? v1 : a * v1;
  uint32_t j0 = (uint32_t)(v * 128 + f0);
  uint32_t bits0 = tf_bits32(k0, k1, j0);
  uint32_t bits1 = tf_bits32(k0, k1, j0 + 1);
  float r0 = (bits0 & 0x80000000u) ? 0.f : 2.f * v0;
  float r1 = (bits1 & 0x80000000u) ? 0.f : 2.f * v1;
  ((float2*)(outbuf + (size_t)v * 128))[lane] = make_float2(r0, r1);
}

// ---- gather layer 2 (16 lanes per node) + bias + prelu + dropout fused ----
__global__ void k_gather2(const int* __restrict__ rowptr, const int* __restrict__ csrc,
                          const float* __restrict__ dis, const float* __restrict__ h2,
                          const float* __restrict__ bias, const float* __restrict__ pa,
                          float* __restrict__ outbuf, int n, uint32_t k0, uint32_t k1) {
  int t = blockIdx.x * blockDim.x + threadIdx.x;
  int v = t >> 4, k = t & 15;
  if (v >= n) return;
  float dv = dis[v];
  float acc = h2[(size_t)v * 16 + k] * dv * dv;
  int beg = rowptr[v], end = rowptr[v + 1];
  for (int j = beg; j < end; ++j) {
    int s = csrc[j];
    acc += h2[(size_t)s * 16 + k] * (dis[s] * dv);
  }
  float a = pa[0];
  float val = acc + bias[k];
  val = val >= 0.f ? val : a * val;
  uint32_t bits = tf_bits32(k0, k1, (uint32_t)(v * 16 + k));
  outbuf[(size_t)v * 16 + k] = (bits & 0x80000000u) ? 0.f : 2.f * val;
}

// ---------------- GEMM2: h2[n,16] = h[n,128] @ W2[128,16] ----------------
__global__ __launch_bounds__(256) void k_gemm2(const float* __restrict__ hin,
                                               const float* __restrict__ W2,
                                               float* __restrict__ h2, int n) {
  __shared__ float xs[64][132];
  const int rowBase = blockIdx.x * 64;
  for (int i = threadIdx.x; i < 64 * 32; i += 256) {
    int r = i >> 5, c4 = i & 31;
    float4 v = make_float4(0.f, 0.f, 0.f, 0.f);
    if (rowBase + r < n)
      v = ((const float4*)(hin + (size_t)(rowBase + r) * 128))[c4];
    *(float4*)&xs[r][c4 * 4] = v;
  }
  __syncthreads();
  const int r = threadIdx.x >> 2;
  const int cg = threadIdx.x & 3;
  float acc[4] = {0.f, 0.f, 0.f, 0.f};
#pragma unroll 4
  for (int k = 0; k < 128; ++k) {
    float xv = xs[r][k];
    const float4 wv = *(const float4*)&W2[k * 16 + cg * 4];
    acc[0] += xv * wv.x;
    acc[1] += xv * wv.y;
    acc[2] += xv * wv.z;
    acc[3] += xv * wv.w;
  }
  int row = rowBase + r;
  if (row < n)
    *(float4*)&h2[(size_t)row * 16 + cg * 4] =
        make_float4(acc[0], acc[1], acc[2], acc[3]);
}

// ---------------- GEMM3: out[n,10] = hp[n,16] @ Wfc[16,10] + bfc ----------------
__global__ void k_gemm3(const float* __restrict__ hp, const float* __restrict__ Wfc,
                        const float* __restrict__ bfc, float* __restrict__ out, int n) {
  int row = blockIdx.x * blockDim.x + threadIdx.x;
  if (row >= n) return;
  float hrow[16];
#pragma unroll
  for (int q = 0; q < 4; ++q) {
    float4 v = ((const float4*)(hp + (size_t)row * 16))[q];
    hrow[q * 4 + 0] = v.x; hrow[q * 4 + 1] = v.y;
    hrow[q * 4 + 2] = v.z; hrow[q * 4 + 3] = v.w;
  }
#pragma unroll
  for (int c = 0; c < 10; ++c) {
    float acc = bfc[c];
#pragma unroll
    for (int k = 0; k < 16; ++k) acc += hrow[k] * Wfc[k * 10 + c];
    out[(size_t)row * 10 + c] = acc;
  }
}

extern "C" void kernel_launch(void* const* d_in, const int* in_sizes, int n_in,
                              void* d_out, int out_size, void* d_ws, size_t ws_size,
                              hipStream_t stream) {
  const float* x   = (const float*)d_in[0];
  const int*   ei  = (const int*)d_in[1];
  const float* W1  = (const float*)d_in[2];
  const float* b1  = (const float*)d_in[3];
  const float* W2  = (const float*)d_in[4];
  const float* b2  = (const float*)d_in[5];
  const float* pa  = (const float*)d_in[6];
  const float* Wfc = (const float*)d_in[7];
  const float* bfc = (const float*)d_in[8];
  float* out = (float*)d_out;

  const int n = in_sizes[0] / 128;
  const int E = in_sizes[1] / 2;
  const int* src = ei;
  const int* dst = ei + E;

  // workspace layout
  char* w = (char*)d_ws;
  float* dis   = (float*)w;                 w += (size_t)n * 4;
  int* rowptr  = (int*)w;                   w += (size_t)(n + 1) * 4;
  int* cursor  = (int*)w;                   w += (size_t)n * 4;
  int* bs      = (int*)w;                   w += 1024;                // block sums
  int* csrc    = (int*)w;                   w += (size_t)E * 4;
  float* bufA  = (float*)w;                 w += (size_t)n * 128 * 4; // h1 -> h2/agg2
  float* bufB  = (float*)w;                 // h (post layer1)
  float* h2    = bufA;
  float* agg2  = bufA + (size_t)n * 16;

  // JAX partitionable threefry key derivation: dk1,dk2 = split(key(42))
  uint32_t dk1_0, dk1_1, dk2_0, dk2_1;
  threefry2x32(0u, 42u, 0u, 0u, &dk1_0, &dk1_1);
  threefry2x32(0u, 42u, 0u, 1u, &dk2_0, &dk2_1);

  const int G = (n + SCAN_CHUNK - 1) / SCAN_CHUNK;  // 98 for n=100000 (<=256)

  // 1. degree (float, includes self-loop)
  k_init_one<<<(n + 255) / 256, 256, 0, stream>>>(dis, n);
  k_deg<<<2048, 256, 0, stream>>>(dst, dis, E);

  // 2. CSR build: rowptr = exscan(deg-1); fill csrc sorted by dst
  k_blocksum<<<G, 256, 0, stream>>>(dis, n, bs);
  k_scanbs<<<1, 256, 0, stream>>>(bs, G);
  k_scanfinal<<<G, 256, 0, stream>>>(dis, n, bs, rowptr, cursor, E);
  k_fill<<<2048, 256, 0, stream>>>(src, dst, cursor, csrc, E);

  // 3. dis = rsqrt(deg)
  k_rsqrt<<<(n + 255) / 256, 256, 0, stream>>>(dis, n);

  // 4. h1 = x @ W1
  k_gemm1<<<(n + 63) / 64, 256, 0, stream>>>(x, W1, bufA, n);

  // 5. layer-1 aggregate + bias + prelu + dropout(dk1)  -> bufB
  k_gather1<<<(n * 64 + 255) / 256, 256, 0, stream>>>(rowptr, csrc, dis, bufA,
                                                      b1, pa, bufB, n, dk1_0, dk1_1);

  // 6. h2 = h @ W2
  k_gemm2<<<(n + 63) / 64, 256, 0, stream>>>(bufB, W2, h2, n);

  // 7. layer-2 aggregate + bias + prelu + dropout(dk2)  -> agg2
  k_gather2<<<(n * 16 + 255) / 256, 256, 0, stream>>>(rowptr, csrc, dis, h2,
                                                      b2, pa, agg2, n, dk2_0, dk2_1);

  // 8. out = agg2 @ Wfc + bfc
  k_gemm3<<<(n + 255) / 256, 256, 0, stream>>>(agg2, Wfc, bfc, out, n);
}

// Round 3
// 436.178 us; speedup vs baseline: 2.2065x; 1.2795x over previous
//
#include <hip/hip_runtime.h>
#include <stdint.h>

// ---------------- threefry2x32 (JAX-compatible, 20 rounds) ----------------
#define TF_ROUND(x0, x1, r)                                                    \
  {                                                                            \
    x0 += x1;                                                                  \
    x1 = (x1 << r) | (x1 >> (32 - r));                                         \
    x1 ^= x0;                                                                  \
  }

__host__ __device__ inline void threefry2x32(uint32_t k0, uint32_t k1,
                                             uint32_t x0, uint32_t x1,
                                             uint32_t* o0, uint32_t* o1) {
  uint32_t ks2 = k0 ^ k1 ^ 0x1BD11BDAu;
  x0 += k0; x1 += k1;
  TF_ROUND(x0, x1, 13) TF_ROUND(x0, x1, 15) TF_ROUND(x0, x1, 26) TF_ROUND(x0, x1, 6)
  x0 += k1; x1 += ks2 + 1u;
  TF_ROUND(x0, x1, 17) TF_ROUND(x0, x1, 29) TF_ROUND(x0, x1, 16) TF_ROUND(x0, x1, 24)
  x0 += ks2; x1 += k0 + 2u;
  TF_ROUND(x0, x1, 13) TF_ROUND(x0, x1, 15) TF_ROUND(x0, x1, 26) TF_ROUND(x0, x1, 6)
  x0 += k0; x1 += k1 + 3u;
  TF_ROUND(x0, x1, 17) TF_ROUND(x0, x1, 29) TF_ROUND(x0, x1, 16) TF_ROUND(x0, x1, 24)
  x0 += k1; x1 += ks2 + 4u;
  TF_ROUND(x0, x1, 13) TF_ROUND(x0, x1, 15) TF_ROUND(x0, x1, 26) TF_ROUND(x0, x1, 6)
  x0 += ks2; x1 += k0 + 5u;
  *o0 = x0; *o1 = x1;
}

__device__ inline uint32_t tf_bits32(uint32_t k0, uint32_t k1, uint32_t ctr) {
  uint32_t a, b;
  threefry2x32(k0, k1, 0u, ctr, &a, &b);
  return a ^ b;
}

// bf16 helpers (RNE pack, bit-shift unpack)
__device__ inline uint32_t f2bf(float f) {
  uint32_t u = __float_as_uint(f);
  return (u + 0x7fffu + ((u >> 16) & 1u)) >> 16;
}
__device__ inline float bf_lo(uint32_t p) { return __uint_as_float(p << 16); }
__device__ inline float bf_hi(uint32_t p) { return __uint_as_float(p & 0xffff0000u); }

// ---------------- degree ----------------
__global__ void k_init_one(float* __restrict__ dis, int n) {
  int i = blockIdx.x * blockDim.x + threadIdx.x;
  if (i < n) dis[i] = 1.0f;  // self-loop contribution
}

__global__ void k_deg(const int* __restrict__ dst, float* __restrict__ dis, int E) {
  int t = blockIdx.x * blockDim.x + threadIdx.x;
  int stride = gridDim.x * blockDim.x;
  for (int e = t; e < E; e += stride) atomicAdd(&dis[dst[e]], 1.0f);
}

__global__ void k_rsqrt(float* __restrict__ dis, int n) {
  int i = blockIdx.x * blockDim.x + threadIdx.x;
  if (i < n) dis[i] = rsqrtf(dis[i]);
}

// ---------------- CSR build: exclusive scan of (deg-1) ----------------
#define SCAN_CHUNK 1024

__global__ __launch_bounds__(256) void k_blocksum(const float* __restrict__ deg,
                                                  int n, int* __restrict__ bs) {
  __shared__ int sdata[256];
  int base = blockIdx.x * SCAN_CHUNK;
  int s = 0;
  for (int i = threadIdx.x; i < SCAN_CHUNK; i += 256) {
    int idx = base + i;
    if (idx < n) s += (int)deg[idx] - 1;
  }
  sdata[threadIdx.x] = s;
  __syncthreads();
  for (int off = 128; off > 0; off >>= 1) {
    if (threadIdx.x < off) sdata[threadIdx.x] += sdata[threadIdx.x + off];
    __syncthreads();
  }
  if (threadIdx.x == 0) bs[blockIdx.x] = sdata[0];
}

__global__ __launch_bounds__(256) void k_scanbs(int* __restrict__ bs, int G) {
  __shared__ int sh[256];
  int v = (threadIdx.x < G) ? bs[threadIdx.x] : 0;
  sh[threadIdx.x] = v;
  __syncthreads();
  for (int off = 1; off < 256; off <<= 1) {
    int t = (threadIdx.x >= off) ? sh[threadIdx.x - off] : 0;
    __syncthreads();
    sh[threadIdx.x] += t;
    __syncthreads();
  }
  if (threadIdx.x < G) bs[threadIdx.x] = sh[threadIdx.x] - v;  // exclusive
}

__global__ __launch_bounds__(256) void k_scanfinal(const float* __restrict__ deg,
                                                   int n, const int* __restrict__ bs,
                                                   int* __restrict__ rowptr,
                                                   int* __restrict__ cursor, int E) {
  __shared__ int sh[256];
  int base = blockIdx.x * SCAN_CHUNK;
  int idx0 = base + threadIdx.x * 4;
  int c[4];
  int local = 0;
#pragma unroll
  for (int q = 0; q < 4; ++q) {
    int idx = idx0 + q;
    c[q] = (idx < n) ? (int)deg[idx] - 1 : 0;
    local += c[q];
  }
  sh[threadIdx.x] = local;
  __syncthreads();
  for (int off = 1; off < 256; off <<= 1) {
    int t = (threadIdx.x >= off) ? sh[threadIdx.x - off] : 0;
    __syncthreads();
    sh[threadIdx.x] += t;
    __syncthreads();
  }
  int pre = bs[blockIdx.x] + sh[threadIdx.x] - local;  // exclusive prefix
#pragma unroll
  for (int q = 0; q < 4; ++q) {
    int idx = idx0 + q;
    if (idx < n) { rowptr[idx] = pre; cursor[idx] = pre; }
    pre += c[q];
  }
  if (blockIdx.x == 0 && threadIdx.x == 0) rowptr[n] = E;
}

__global__ void k_fill(const int* __restrict__ src, const int* __restrict__ dst,
                       int* __restrict__ cursor, int* __restrict__ csrc, int E) {
  int t = blockIdx.x * blockDim.x + threadIdx.x;
  int stride = gridDim.x * blockDim.x;
  for (int e = t; e < E; e += stride) {
    int slot = atomicAdd(&cursor[dst[e]], 1);
    csrc[slot] = src[e];
  }
}

// ---- GEMM1: h1[n,128] = x[n,128] @ W[128,128], output packed bf16 ----
__global__ __launch_bounds__(256) void k_gemm1(const float* __restrict__ x,
                                               const float* __restrict__ W,
                                               uint16_t* __restrict__ h, int n) {
  __shared__ float xs[64][128];
  const int rowBase = blockIdx.x * 64;
  for (int i = threadIdx.x; i < 64 * 32; i += 256) {
    int r = i >> 5, c4 = i & 31;
    float4 v = make_float4(0.f, 0.f, 0.f, 0.f);
    if (rowBase + r < n)
      v = ((const float4*)(x + (size_t)(rowBase + r) * 128))[c4];
    *(float4*)&xs[r][c4 * 4] = v;
  }
  __syncthreads();
  const int tc = threadIdx.x & 31;
  const int tr = threadIdx.x >> 5;
  float acc[8][4];
#pragma unroll
  for (int r = 0; r < 8; ++r)
#pragma unroll
    for (int c = 0; c < 4; ++c) acc[r][c] = 0.f;
#pragma unroll 4
  for (int k = 0; k < 128; ++k) {
    const float4 wv = *(const float4*)&W[k * 128 + tc * 4];
    float xr[8];
#pragma unroll
    for (int r = 0; r < 8; ++r) xr[r] = xs[tr * 8 + r][k];
#pragma unroll
    for (int r = 0; r < 8; ++r) {
      acc[r][0] += xr[r] * wv.x;
      acc[r][1] += xr[r] * wv.y;
      acc[r][2] += xr[r] * wv.z;
      acc[r][3] += xr[r] * wv.w;
    }
  }
#pragma unroll
  for (int r = 0; r < 8; ++r) {
    int row = rowBase + tr * 8 + r;
    if (row < n) {
      uint32_t lo = f2bf(acc[r][0]) | (f2bf(acc[r][1]) << 16);
      uint32_t hi = f2bf(acc[r][2]) | (f2bf(acc[r][3]) << 16);
      ((uint2*)(h + (size_t)row * 128))[tc] = make_uint2(lo, hi);
    }
  }
}

// ---- gather layer 1: one wave/node, bf16 rows, shfl-broadcast prefetch ----
__global__ __launch_bounds__(256) void k_gather1(
    const int* __restrict__ rowptr, const int* __restrict__ csrc,
    const float* __restrict__ dis, const uint16_t* __restrict__ h1,
    const float* __restrict__ bias, const float* __restrict__ pa,
    float* __restrict__ outbuf, int n, uint32_t k0, uint32_t k1) {
  int lane = threadIdx.x & 63;
  int v = (blockIdx.x * blockDim.x + threadIdx.x) >> 6;
  if (v >= n) return;
  float dv = dis[v];
  uint32_t selfp = ((const uint32_t*)(h1 + (size_t)v * 128))[lane];
  float wself = dv * dv;
  float accx = bf_lo(selfp) * wself;
  float accy = bf_hi(selfp) * wself;
  int beg = rowptr[v];
  int deg = rowptr[v + 1] - beg;
  for (int base = 0; base < deg; base += 64) {
    int cnt = min(64, deg - base);
    int idx = base + lane;
    int sv = 0;
    float svd = 0.f;
    if (idx < deg) {
      sv = csrc[beg + idx];
      svd = dis[sv];
    }
    int j = 0;
    for (; j + 4 <= cnt; j += 4) {
      int s0 = __shfl(sv, j), s1 = __shfl(sv, j + 1);
      int s2 = __shfl(sv, j + 2), s3 = __shfl(sv, j + 3);
      float w0 = __shfl(svd, j) * dv, w1 = __shfl(svd, j + 1) * dv;
      float w2 = __shfl(svd, j + 2) * dv, w3 = __shfl(svd, j + 3) * dv;
      uint32_t r0 = ((const uint32_t*)(h1 + (size_t)s0 * 128))[lane];
      uint32_t r1 = ((const uint32_t*)(h1 + (size_t)s1 * 128))[lane];
      uint32_t r2 = ((const uint32_t*)(h1 + (size_t)s2 * 128))[lane];
      uint32_t r3 = ((const uint32_t*)(h1 + (size_t)s3 * 128))[lane];
      accx += bf_lo(r0) * w0; accy += bf_hi(r0) * w0;
      accx += bf_lo(r1) * w1; accy += bf_hi(r1) * w1;
      accx += bf_lo(r2) * w2; accy += bf_hi(r2) * w2;
      accx += bf_lo(r3) * w3; accy += bf_hi(r3) * w3;
    }
    for (; j < cnt; ++j) {
      int s = __shfl(sv, j);
      float w = __shfl(svd, j) * dv;
      uint32_t r = ((const uint32_t*)(h1 + (size_t)s * 128))[lane];
      accx += bf_lo(r) * w;
      accy += bf_hi(r) * w;
    }
  }
  float a = pa[0];
  int f0 = lane * 2;
  float v0 = accx + bias[f0];
  float v1 = accy + bias[f0 + 1];
  v0 = v0 >= 0.f ? v0 : a * v0;
  v1 = v1 >= 0.f ? v1 : a * v1;
  uint32_t j0 = (uint32_t)v * 128u + (uint32_t)f0;
  uint32_t bits0 = tf_bits32(k0, k1, j0);
  uint32_t bits1 = tf_bits32(k0, k1, j0 + 1);
  float r0 = (bits0 & 0x80000000u) ? 0.f : 2.f * v0;
  float r1 = (bits1 & 0x80000000u) ? 0.f : 2.f * v1;
  ((float2*)(outbuf + (size_t)v * 128))[lane] = make_float2(r0, r1);
}

// ---- gather layer 2: 16-lane groups, shfl(width=16) prefetch ----
__global__ __launch_bounds__(256) void k_gather2(
    const int* __restrict__ rowptr, const int* __restrict__ csrc,
    const float* __restrict__ dis, const float* __restrict__ h2,
    const float* __restrict__ bias, const float* __restrict__ pa,
    float* __restrict__ outbuf, int n, uint32_t k0, uint32_t k1) {
  int t = blockIdx.x * blockDim.x + threadIdx.x;
  int v = t >> 4, k = t & 15;
  if (v >= n) return;
  float dv = dis[v];
  float acc = h2[(size_t)v * 16 + k] * dv * dv;
  int beg = rowptr[v];
  int deg = rowptr[v + 1] - beg;
  for (int base = 0; base < deg; base += 16) {
    int cnt = min(16, deg - base);
    int idx = base + k;
    int sv = 0;
    float svd = 0.f;
    if (idx < deg) {
      sv = csrc[beg + idx];
      svd = dis[sv];
    }
    int j = 0;
    for (; j + 4 <= cnt; j += 4) {
      int s0 = __shfl(sv, j, 16), s1 = __shfl(sv, j + 1, 16);
      int s2 = __shfl(sv, j + 2, 16), s3 = __shfl(sv, j + 3, 16);
      float w0 = __shfl(svd, j, 16) * dv, w1 = __shfl(svd, j + 1, 16) * dv;
      float w2 = __shfl(svd, j + 2, 16) * dv, w3 = __shfl(svd, j + 3, 16) * dv;
      float x0 = h2[(size_t)s0 * 16 + k], x1 = h2[(size_t)s1 * 16 + k];
      float x2 = h2[(size_t)s2 * 16 + k], x3 = h2[(size_t)s3 * 16 + k];
      acc += x0 * w0 + x1 * w1 + x2 * w2 + x3 * w3;
    }
    for (; j < cnt; ++j) {
      int s = __shfl(sv, j, 16);
      float w = __shfl(svd, j, 16) * dv;
      acc += h2[(size_t)s * 16 + k] * w;
    }
  }
  float a = pa[0];
  float val = acc + bias[k];
  val = val >= 0.f ? val : a * val;
  uint32_t bits = tf_bits32(k0, k1, (uint32_t)v * 16u + (uint32_t)k);
  outbuf[(size_t)v * 16 + k] = (bits & 0x80000000u) ? 0.f : 2.f * val;
}

// ---------------- GEMM2: h2[n,16] = h[n,128] @ W2[128,16] ----------------
__global__ __launch_bounds__(256) void k_gemm2(const float* __restrict__ hin,
                                               const float* __restrict__ W2,
                                               float* __restrict__ h2, int n) {
  __shared__ float xs[64][132];
  const int rowBase = blockIdx.x * 64;
  for (int i = threadIdx.x; i < 64 * 32; i += 256) {
    int r = i >> 5, c4 = i & 31;
    float4 v = make_float4(0.f, 0.f, 0.f, 0.f);
    if (rowBase + r < n)
      v = ((const float4*)(hin + (size_t)(rowBase + r) * 128))[c4];
    *(float4*)&xs[r][c4 * 4] = v;
  }
  __syncthreads();
  const int r = threadIdx.x >> 2;
  const int cg = threadIdx.x & 3;
  float acc[4] = {0.f, 0.f, 0.f, 0.f};
#pragma unroll 4
  for (int k = 0; k < 128; ++k) {
    float xv = xs[r][k];
    const float4 wv = *(const float4*)&W2[k * 16 + cg * 4];
    acc[0] += xv * wv.x;
    acc[1] += xv * wv.y;
    acc[2] += xv * wv.z;
    acc[3] += xv * wv.w;
  }
  int row = rowBase + r;
  if (row < n)
    *(float4*)&h2[(size_t)row * 16 + cg * 4] =
        make_float4(acc[0], acc[1], acc[2], acc[3]);
}

// ---------------- GEMM3: out[n,10] = hp[n,16] @ Wfc[16,10] + bfc ----------------
__global__ void k_gemm3(const float* __restrict__ hp, const float* __restrict__ Wfc,
                        const float* __restrict__ bfc, float* __restrict__ out, int n) {
  int row = blockIdx.x * blockDim.x + threadIdx.x;
  if (row >= n) return;
  float hrow[16];
#pragma unroll
  for (int q = 0; q < 4; ++q) {
    float4 v = ((const float4*)(hp + (size_t)row * 16))[q];
    hrow[q * 4 + 0] = v.x; hrow[q * 4 + 1] = v.y;
    hrow[q * 4 + 2] = v.z; hrow[q * 4 + 3] = v.w;
  }
#pragma unroll
  for (int c = 0; c < 10; ++c) {
    float acc = bfc[c];
#pragma unroll
    for (int k = 0; k < 16; ++k) acc += hrow[k] * Wfc[k * 10 + c];
    out[(size_t)row * 10 + c] = acc;
  }
}

extern "C" void kernel_launch(void* const* d_in, const int* in_sizes, int n_in,
                              void* d_out, int out_size, void* d_ws, size_t ws_size,
                              hipStream_t stream) {
  const float* x   = (const float*)d_in[0];
  const int*   ei  = (const int*)d_in[1];
  const float* W1  = (const float*)d_in[2];
  const float* b1  = (const float*)d_in[3];
  const float* W2  = (const float*)d_in[4];
  const float* b2  = (const float*)d_in[5];
  const float* pa  = (const float*)d_in[6];
  const float* Wfc = (const float*)d_in[7];
  const float* bfc = (const float*)d_in[8];
  float* out = (float*)d_out;

  const int n = in_sizes[0] / 128;
  const int E = in_sizes[1] / 2;
  const int* src = ei;
  const int* dst = ei + E;

  // workspace layout
  char* w = (char*)d_ws;
  float* dis      = (float*)w;              w += (size_t)n * 4;
  int* rowptr     = (int*)w;                w += (size_t)(n + 1) * 4;
  int* cursor     = (int*)w;                w += (size_t)n * 4;
  int* bs         = (int*)w;                w += 1024;
  int* csrc       = (int*)w;                w += (size_t)E * 4;
  uint16_t* h1bf  = (uint16_t*)w;           w += (size_t)n * 128 * 2;  // bf16 h1
  float* bufB     = (float*)w;              w += (size_t)n * 128 * 4;  // h post-L1
  float* h2       = (float*)h1bf;           // reuse: n*16 fp32
  float* agg2     = h2 + (size_t)n * 16;    // n*16 fp32

  // JAX partitionable threefry key derivation: dk1,dk2 = split(key(42))
  uint32_t dk1_0, dk1_1, dk2_0, dk2_1;
  threefry2x32(0u, 42u, 0u, 0u, &dk1_0, &dk1_1);
  threefry2x32(0u, 42u, 0u, 1u, &dk2_0, &dk2_1);

  const int G = (n + SCAN_CHUNK - 1) / SCAN_CHUNK;

  // 1. degree (float, includes self-loop)
  k_init_one<<<(n + 255) / 256, 256, 0, stream>>>(dis, n);
  k_deg<<<2048, 256, 0, stream>>>(dst, dis, E);

  // 2. CSR build
  k_blocksum<<<G, 256, 0, stream>>>(dis, n, bs);
  k_scanbs<<<1, 256, 0, stream>>>(bs, G);
  k_scanfinal<<<G, 256, 0, stream>>>(dis, n, bs, rowptr, cursor, E);
  k_fill<<<2048, 256, 0, stream>>>(src, dst, cursor, csrc, E);

  // 3. dis = rsqrt(deg)
  k_rsqrt<<<(n + 255) / 256, 256, 0, stream>>>(dis, n);

  // 4. h1 = x @ W1  (bf16 output)
  k_gemm1<<<(n + 63) / 64, 256, 0, stream>>>(x, W1, h1bf, n);

  // 5. layer-1 aggregate + bias + prelu + dropout(dk1) -> bufB (fp32)
  k_gather1<<<(n * 64 + 255) / 256, 256, 0, stream>>>(rowptr, csrc, dis, h1bf,
                                                      b1, pa, bufB, n, dk1_0, dk1_1);

  // 6. h2 = h @ W2
  k_gemm2<<<(n + 63) / 64, 256, 0, stream>>>(bufB, W2, h2, n);

  // 7. layer-2 aggregate + bias + prelu + dropout(dk2) -> agg2
  k_gather2<<<(n * 16 + 255) / 256, 256, 0, stream>>>(rowptr, csrc, dis, h2,
                                                      b2, pa, agg2, n, dk2_0, dk2_1);

  // 8. out = agg2 @ Wfc + bfc
  k_gemm3<<<(n + 255) / 256, 256, 0, stream>>>(agg2, Wfc, bfc, out, n);
}

// Round 4
// 296.588 us; speedup vs baseline: 3.2449x; 1.4707x over previous
//
#include <hip/hip_runtime.h>
#include <stdint.h>

#define G1  128   // blocks for hist/scatter passes
#define BSH 9     // log2(nodes per bucket)
#define BSZ 512   // nodes per bucket

// ---------------- threefry2x32 (JAX-compatible, 20 rounds) ----------------
#define TF_ROUND(x0, x1, r)                                                    \
  {                                                                            \
    x0 += x1;                                                                  \
    x1 = (x1 << r) | (x1 >> (32 - r));                                         \
    x1 ^= x0;                                                                  \
  }

__host__ __device__ inline void threefry2x32(uint32_t k0, uint32_t k1,
                                             uint32_t x0, uint32_t x1,
                                             uint32_t* o0, uint32_t* o1) {
  uint32_t ks2 = k0 ^ k1 ^ 0x1BD11BDAu;
  x0 += k0; x1 += k1;
  TF_ROUND(x0, x1, 13) TF_ROUND(x0, x1, 15) TF_ROUND(x0, x1, 26) TF_ROUND(x0, x1, 6)
  x0 += k1; x1 += ks2 + 1u;
  TF_ROUND(x0, x1, 17) TF_ROUND(x0, x1, 29) TF_ROUND(x0, x1, 16) TF_ROUND(x0, x1, 24)
  x0 += ks2; x1 += k0 + 2u;
  TF_ROUND(x0, x1, 13) TF_ROUND(x0, x1, 15) TF_ROUND(x0, x1, 26) TF_ROUND(x0, x1, 6)
  x0 += k0; x1 += k1 + 3u;
  TF_ROUND(x0, x1, 17) TF_ROUND(x0, x1, 29) TF_ROUND(x0, x1, 16) TF_ROUND(x0, x1, 24)
  x0 += k1; x1 += ks2 + 4u;
  TF_ROUND(x0, x1, 13) TF_ROUND(x0, x1, 15) TF_ROUND(x0, x1, 26) TF_ROUND(x0, x1, 6)
  x0 += ks2; x1 += k0 + 5u;
  *o0 = x0; *o1 = x1;
}

__device__ inline uint32_t tf_bits32(uint32_t k0, uint32_t k1, uint32_t ctr) {
  uint32_t a, b;
  threefry2x32(k0, k1, 0u, ctr, &a, &b);
  return a ^ b;
}

// bf16 helpers (RNE pack, bit-shift unpack)
__device__ inline uint32_t f2bf(float f) {
  uint32_t u = __float_as_uint(f);
  return (u + 0x7fffu + ((u >> 16) & 1u)) >> 16;
}
__device__ inline float bf_lo(uint32_t p) { return __uint_as_float(p << 16); }
__device__ inline float bf_hi(uint32_t p) { return __uint_as_float(p & 0xffff0000u); }

// ---------------- bucket counting-sort graph build ----------------
// pass 1: per-block histogram of dst buckets, bucket-major layout [NB][G1]
__global__ __launch_bounds__(256) void k_bhist(const int* __restrict__ dst,
                                               int* __restrict__ hist_t,
                                               int E, int NB, int chunk) {
  __shared__ int hist[256];
  for (int b = threadIdx.x; b < NB; b += 256) hist[b] = 0;
  __syncthreads();
  int e0 = blockIdx.x * chunk;
  int e1 = min(e0 + chunk, E);
  for (int e = e0 + threadIdx.x; e < e1; e += 256)
    atomicAdd(&hist[dst[e] >> BSH], 1);
  __syncthreads();
  for (int b = threadIdx.x; b < NB; b += 256)
    hist_t[b * G1 + blockIdx.x] = hist[b];
}

// pass 2: exclusive scan in place over hist_t[0..T); hist_t[T] = total (=E)
__global__ __launch_bounds__(1024) void k_bscan(int* __restrict__ h, int T) {
  __shared__ int sh[1024];
  int per = (T + 1023) >> 10;
  int b0 = threadIdx.x * per;
  int b1 = min(b0 + per, T);
  if (b0 > T) b0 = T;
  int s = 0;
  for (int i = b0; i < b1; ++i) s += h[i];
  sh[threadIdx.x] = s;
  __syncthreads();
  for (int off = 1; off < 1024; off <<= 1) {
    int t = (threadIdx.x >= off) ? sh[threadIdx.x - off] : 0;
    __syncthreads();
    sh[threadIdx.x] += t;
    __syncthreads();
  }
  int run = sh[threadIdx.x] - s;  // exclusive prefix
  for (int i = b0; i < b1; ++i) { int v = h[i]; h[i] = run; run += v; }
  if (threadIdx.x == 1023) h[T] = run;
}

// pass 3: scatter packed (src<<9 | dst&511) into reserved per-(bucket,block) ranges
__global__ __launch_bounds__(256) void k_bscatter(const int* __restrict__ src,
                                                  const int* __restrict__ dst,
                                                  const int* __restrict__ scanned,
                                                  uint32_t* __restrict__ ebuf,
                                                  int E, int NB, int chunk) {
  __shared__ int cur[256];
  int g = blockIdx.x;
  for (int b = threadIdx.x; b < NB; b += 256) cur[b] = scanned[b * G1 + g];
  __syncthreads();
  int e0 = g * chunk, e1 = min(e0 + chunk, E);
  for (int e = e0 + threadIdx.x; e < e1; e += 256) {
    int d = dst[e];
    int slot = atomicAdd(&cur[d >> BSH], 1);
    ebuf[slot] = ((uint32_t)src[e] << BSH) | (uint32_t)(d & (BSZ - 1));
  }
}

// pass 4: per-bucket: degree count (LDS), rowptr = segbase + local scan,
// dis = rsqrt(deg+1), csrc fill — all fused, no global atomics.
__global__ __launch_bounds__(256) void k_bfinal(const uint32_t* __restrict__ ebuf,
                                                const int* __restrict__ scanned,
                                                int* __restrict__ rowptr,
                                                float* __restrict__ dis,
                                                int* __restrict__ csrc,
                                                int n, int NB, int E) {
  __shared__ int cnt[BSZ];
  __shared__ int sc[256];
  int b = blockIdx.x;
  int t = threadIdx.x;
  int seg0 = scanned[b * G1];
  int seg1 = scanned[(b + 1) * G1];  // b==NB-1 hits the h[T]=E sentinel
  for (int i = t; i < BSZ; i += 256) cnt[i] = 0;
  __syncthreads();
  for (int i = seg0 + t; i < seg1; i += 256)
    atomicAdd(&cnt[ebuf[i] & (BSZ - 1)], 1);
  __syncthreads();
  int a0 = cnt[2 * t], a1 = cnt[2 * t + 1];
  int s = a0 + a1;
  sc[t] = s;
  __syncthreads();
  for (int off = 1; off < 256; off <<= 1) {
    int tmp = (t >= off) ? sc[t - off] : 0;
    __syncthreads();
    sc[t] += tmp;
    __syncthreads();
  }
  int pre = sc[t] - s;  // exclusive over pairs
  int node0 = b * BSZ;
  int p0 = seg0 + pre;
  int p1 = p0 + a0;
  int nd0 = node0 + 2 * t, nd1 = nd0 + 1;
  if (nd0 <= n) rowptr[nd0] = p0;
  if (nd1 <= n) rowptr[nd1] = p1;
  if (nd0 < n) dis[nd0] = rsqrtf((float)(a0 + 1));
  if (nd1 < n) dis[nd1] = rsqrtf((float)(a1 + 1));
  cnt[2 * t] = p0;      // each thread only touches its own 2 slots
  cnt[2 * t + 1] = p1;
  __syncthreads();
  for (int i = seg0 + t; i < seg1; i += 256) {
    uint32_t u = ebuf[i];
    int slot = atomicAdd(&cnt[u & (BSZ - 1)], 1);
    csrc[slot] = (int)(u >> BSH);
  }
  if (b == NB - 1 && t == 0) rowptr[n] = E;
}

// ---- GEMM1: h1[n,128] = x[n,128] @ W[128,128], output packed bf16 ----
__global__ __launch_bounds__(256) void k_gemm1(const float* __restrict__ x,
                                               const float* __restrict__ W,
                                               uint16_t* __restrict__ h, int n) {
  __shared__ float xs[64][128];
  const int rowBase = blockIdx.x * 64;
  for (int i = threadIdx.x; i < 64 * 32; i += 256) {
    int r = i >> 5, c4 = i & 31;
    float4 v = make_float4(0.f, 0.f, 0.f, 0.f);
    if (rowBase + r < n)
      v = ((const float4*)(x + (size_t)(rowBase + r) * 128))[c4];
    *(float4*)&xs[r][c4 * 4] = v;
  }
  __syncthreads();
  const int tc = threadIdx.x & 31;
  const int tr = threadIdx.x >> 5;
  float acc[8][4];
#pragma unroll
  for (int r = 0; r < 8; ++r)
#pragma unroll
    for (int c = 0; c < 4; ++c) acc[r][c] = 0.f;
#pragma unroll 4
  for (int k = 0; k < 128; ++k) {
    const float4 wv = *(const float4*)&W[k * 128 + tc * 4];
    float xr[8];
#pragma unroll
    for (int r = 0; r < 8; ++r) xr[r] = xs[tr * 8 + r][k];
#pragma unroll
    for (int r = 0; r < 8; ++r) {
      acc[r][0] += xr[r] * wv.x;
      acc[r][1] += xr[r] * wv.y;
      acc[r][2] += xr[r] * wv.z;
      acc[r][3] += xr[r] * wv.w;
    }
  }
#pragma unroll
  for (int r = 0; r < 8; ++r) {
    int row = rowBase + tr * 8 + r;
    if (row < n) {
      uint32_t lo = f2bf(acc[r][0]) | (f2bf(acc[r][1]) << 16);
      uint32_t hi = f2bf(acc[r][2]) | (f2bf(acc[r][3]) << 16);
      ((uint2*)(h + (size_t)row * 128))[tc] = make_uint2(lo, hi);
    }
  }
}

// ---- gather layer 1: one wave/node, bf16 rows, shfl-broadcast prefetch ----
__global__ __launch_bounds__(256) void k_gather1(
    const int* __restrict__ rowptr, const int* __restrict__ csrc,
    const float* __restrict__ dis, const uint16_t* __restrict__ h1,
    const float* __restrict__ bias, const float* __restrict__ pa,
    float* __restrict__ outbuf, int n, uint32_t k0, uint32_t k1) {
  int lane = threadIdx.x & 63;
  int v = (blockIdx.x * blockDim.x + threadIdx.x) >> 6;
  if (v >= n) return;
  float dv = dis[v];
  uint32_t selfp = ((const uint32_t*)(h1 + (size_t)v * 128))[lane];
  float wself = dv * dv;
  float accx = bf_lo(selfp) * wself;
  float accy = bf_hi(selfp) * wself;
  int beg = rowptr[v];
  int deg = rowptr[v + 1] - beg;
  for (int base = 0; base < deg; base += 64) {
    int cnt = min(64, deg - base);
    int idx = base + lane;
    int sv = 0;
    float svd = 0.f;
    if (idx < deg) {
      sv = csrc[beg + idx];
      svd = dis[sv];
    }
    int j = 0;
    for (; j + 4 <= cnt; j += 4) {
      int s0 = __shfl(sv, j), s1 = __shfl(sv, j + 1);
      int s2 = __shfl(sv, j + 2), s3 = __shfl(sv, j + 3);
      float w0 = __shfl(svd, j) * dv, w1 = __shfl(svd, j + 1) * dv;
      float w2 = __shfl(svd, j + 2) * dv, w3 = __shfl(svd, j + 3) * dv;
      uint32_t r0 = ((const uint32_t*)(h1 + (size_t)s0 * 128))[lane];
      uint32_t r1 = ((const uint32_t*)(h1 + (size_t)s1 * 128))[lane];
      uint32_t r2 = ((const uint32_t*)(h1 + (size_t)s2 * 128))[lane];
      uint32_t r3 = ((const uint32_t*)(h1 + (size_t)s3 * 128))[lane];
      accx += bf_lo(r0) * w0; accy += bf_hi(r0) * w0;
      accx += bf_lo(r1) * w1; accy += bf_hi(r1) * w1;
      accx += bf_lo(r2) * w2; accy += bf_hi(r2) * w2;
      accx += bf_lo(r3) * w3; accy += bf_hi(r3) * w3;
    }
    for (; j < cnt; ++j) {
      int s = __shfl(sv, j);
      float w = __shfl(svd, j) * dv;
      uint32_t r = ((const uint32_t*)(h1 + (size_t)s * 128))[lane];
      accx += bf_lo(r) * w;
      accy += bf_hi(r) * w;
    }
  }
  float a = pa[0];
  int f0 = lane * 2;
  float v0 = accx + bias[f0];
  float v1 = accy + bias[f0 + 1];
  v0 = v0 >= 0.f ? v0 : a * v0;
  v1 = v1 >= 0.f ? v1 : a * v1;
  uint32_t j0 = (uint32_t)v * 128u + (uint32_t)f0;
  uint32_t bits0 = tf_bits32(k0, k1, j0);
  uint32_t bits1 = tf_bits32(k0, k1, j0 + 1);
  float r0 = (bits0 & 0x80000000u) ? 0.f : 2.f * v0;
  float r1 = (bits1 & 0x80000000u) ? 0.f : 2.f * v1;
  ((float2*)(outbuf + (size_t)v * 128))[lane] = make_float2(r0, r1);
}

// ---- gather layer 2: 16-lane groups, shfl(width=16) prefetch ----
__global__ __launch_bounds__(256) void k_gather2(
    const int* __restrict__ rowptr, const int* __restrict__ csrc,
    const float* __restrict__ dis, const float* __restrict__ h2,
    const float* __restrict__ bias, const float* __restrict__ pa,
    float* __restrict__ outbuf, int n, uint32_t k0, uint32_t k1) {
  int t = blockIdx.x * blockDim.x + threadIdx.x;
  int v = t >> 4, k = t & 15;
  if (v >= n) return;
  float dv = dis[v];
  float acc = h2[(size_t)v * 16 + k] * dv * dv;
  int beg = rowptr[v];
  int deg = rowptr[v + 1] - beg;
  for (int base = 0; base < deg; base += 16) {
    int cnt = min(16, deg - base);
    int idx = base + k;
    int sv = 0;
    float svd = 0.f;
    if (idx < deg) {
      sv = csrc[beg + idx];
      svd = dis[sv];
    }
    int j = 0;
    for (; j + 4 <= cnt; j += 4) {
      int s0 = __shfl(sv, j, 16), s1 = __shfl(sv, j + 1, 16);
      int s2 = __shfl(sv, j + 2, 16), s3 = __shfl(sv, j + 3, 16);
      float w0 = __shfl(svd, j, 16) * dv, w1 = __shfl(svd, j + 1, 16) * dv;
      float w2 = __shfl(svd, j + 2, 16) * dv, w3 = __shfl(svd, j + 3, 16) * dv;
      float x0 = h2[(size_t)s0 * 16 + k], x1 = h2[(size_t)s1 * 16 + k];
      float x2 = h2[(size_t)s2 * 16 + k], x3 = h2[(size_t)s3 * 16 + k];
      acc += x0 * w0 + x1 * w1 + x2 * w2 + x3 * w3;
    }
    for (; j < cnt; ++j) {
      int s = __shfl(sv, j, 16);
      float w = __shfl(svd, j, 16) * dv;
      acc += h2[(size_t)s * 16 + k] * w;
    }
  }
  float a = pa[0];
  float val = acc + bias[k];
  val = val >= 0.f ? val : a * val;
  uint32_t bits = tf_bits32(k0, k1, (uint32_t)v * 16u + (uint32_t)k);
  outbuf[(size_t)v * 16 + k] = (bits & 0x80000000u) ? 0.f : 2.f * val;
}

// ---------------- GEMM2: h2[n,16] = h[n,128] @ W2[128,16] ----------------
__global__ __launch_bounds__(256) void k_gemm2(const float* __restrict__ hin,
                                               const float* __restrict__ W2,
                                               float* __restrict__ h2, int n) {
  __shared__ float xs[64][132];
  const int rowBase = blockIdx.x * 64;
  for (int i = threadIdx.x; i < 64 * 32; i += 256) {
    int r = i >> 5, c4 = i & 31;
    float4 v = make_float4(0.f, 0.f, 0.f, 0.f);
    if (rowBase + r < n)
      v = ((const float4*)(hin + (size_t)(rowBase + r) * 128))[c4];
    *(float4*)&xs[r][c4 * 4] = v;
  }
  __syncthreads();
  const int r = threadIdx.x >> 2;
  const int cg = threadIdx.x & 3;
  float acc[4] = {0.f, 0.f, 0.f, 0.f};
#pragma unroll 4
  for (int k = 0; k < 128; ++k) {
    float xv = xs[r][k];
    const float4 wv = *(const float4*)&W2[k * 16 + cg * 4];
    acc[0] += xv * wv.x;
    acc[1] += xv * wv.y;
    acc[2] += xv * wv.z;
    acc[3] += xv * wv.w;
  }
  int row = rowBase + r;
  if (row < n)
    *(float4*)&h2[(size_t)row * 16 + cg * 4] =
        make_float4(acc[0], acc[1], acc[2], acc[3]);
}

// ---------------- GEMM3: out[n,10] = hp[n,16] @ Wfc[16,10] + bfc ----------------
__global__ void k_gemm3(const float* __restrict__ hp, const float* __restrict__ Wfc,
                        const float* __restrict__ bfc, float* __restrict__ out, int n) {
  int row = blockIdx.x * blockDim.x + threadIdx.x;
  if (row >= n) return;
  float hrow[16];
#pragma unroll
  for (int q = 0; q < 4; ++q) {
    float4 v = ((const float4*)(hp + (size_t)row * 16))[q];
    hrow[q * 4 + 0] = v.x; hrow[q * 4 + 1] = v.y;
    hrow[q * 4 + 2] = v.z; hrow[q * 4 + 3] = v.w;
  }
#pragma unroll
  for (int c = 0; c < 10; ++c) {
    float acc = bfc[c];
#pragma unroll
    for (int k = 0; k < 16; ++k) acc += hrow[k] * Wfc[k * 10 + c];
    out[(size_t)row * 10 + c] = acc;
  }
}

extern "C" void kernel_launch(void* const* d_in, const int* in_sizes, int n_in,
                              void* d_out, int out_size, void* d_ws, size_t ws_size,
                              hipStream_t stream) {
  const float* x   = (const float*)d_in[0];
  const int*   ei  = (const int*)d_in[1];
  const float* W1  = (const float*)d_in[2];
  const float* b1  = (const float*)d_in[3];
  const float* W2  = (const float*)d_in[4];
  const float* b2  = (const float*)d_in[5];
  const float* pa  = (const float*)d_in[6];
  const float* Wfc = (const float*)d_in[7];
  const float* bfc = (const float*)d_in[8];
  float* out = (float*)d_out;

  const int n = in_sizes[0] / 128;
  const int E = in_sizes[1] / 2;
  const int* src = ei;
  const int* dst = ei + E;

  const int NB = (n + BSZ - 1) / BSZ;       // 196 for n=100000 (<=256)
  const int T = NB * G1;
  const int chunk = (E + G1 - 1) / G1;

  // workspace layout (256B-aligned regions)
  char* w = (char*)d_ws;
  auto alloc = [&](size_t bytes) {
    char* p = w;
    w += (bytes + 255) & ~(size_t)255;
    return p;
  };
  float* dis      = (float*)alloc((size_t)n * 4);
  int* rowptr     = (int*)alloc((size_t)(n + 1) * 4);
  int* hist_t     = (int*)alloc((size_t)(T + 1) * 4);
  uint32_t* ebuf  = (uint32_t*)alloc((size_t)E * 4);
  int* csrc       = (int*)alloc((size_t)E * 4);
  uint16_t* h1bf  = (uint16_t*)alloc((size_t)n * 128 * 2);
  float* bufB     = (float*)alloc((size_t)n * 128 * 4);
  float* h2       = (float*)h1bf;           // reuse after gather1: n*16 fp32
  float* agg2     = h2 + (size_t)n * 16;    // n*16 fp32

  // JAX partitionable threefry key derivation: dk1,dk2 = split(key(42))
  uint32_t dk1_0, dk1_1, dk2_0, dk2_1;
  threefry2x32(0u, 42u, 0u, 0u, &dk1_0, &dk1_1);
  threefry2x32(0u, 42u, 0u, 1u, &dk2_0, &dk2_1);

  // 1. graph build: bucket counting sort -> rowptr, dis, csrc
  k_bhist<<<G1, 256, 0, stream>>>(dst, hist_t, E, NB, chunk);
  k_bscan<<<1, 1024, 0, stream>>>(hist_t, T);
  k_bscatter<<<G1, 256, 0, stream>>>(src, dst, hist_t, ebuf, E, NB, chunk);
  k_bfinal<<<NB, 256, 0, stream>>>(ebuf, hist_t, rowptr, dis, csrc, n, NB, E);

  // 2. h1 = x @ W1  (bf16 output)
  k_gemm1<<<(n + 63) / 64, 256, 0, stream>>>(x, W1, h1bf, n);

  // 3. layer-1 aggregate + bias + prelu + dropout(dk1) -> bufB (fp32)
  k_gather1<<<(n * 64 + 255) / 256, 256, 0, stream>>>(rowptr, csrc, dis, h1bf,
                                                      b1, pa, bufB, n, dk1_0, dk1_1);

  // 4. h2 = h @ W2
  k_gemm2<<<(n + 63) / 64, 256, 0, stream>>>(bufB, W2, h2, n);

  // 5. layer-2 aggregate + bias + prelu + dropout(dk2) -> agg2
  k_gather2<<<(n * 16 + 255) / 256, 256, 0, stream>>>(rowptr, csrc, dis, h2,
                                                      b2, pa, agg2, n, dk2_0, dk2_1);

  // 6. out = agg2 @ Wfc + bfc
  k_gemm3<<<(n + 255) / 256, 256, 0, stream>>>(agg2, Wfc, bfc, out, n);
}

// Round 5
// 266.723 us; speedup vs baseline: 3.6083x; 1.1120x over previous
//
#include <hip/hip_runtime.h>
#include <stdint.h>

#define G1  128   // blocks for hist/scatter passes
#define BSH 9     // log2(nodes per bucket)
#define BSZ 512   // nodes per bucket

typedef __attribute__((ext_vector_type(8))) short short8;
typedef __attribute__((ext_vector_type(4))) float f32x4;

// ---------------- threefry2x32 (JAX-compatible, 20 rounds) ----------------
#define TF_ROUND(x0, x1, r)                                                    \
  {                                                                            \
    x0 += x1;                                                                  \
    x1 = (x1 << r) | (x1 >> (32 - r));                                         \
    x1 ^= x0;                                                                  \
  }

__host__ __device__ inline void threefry2x32(uint32_t k0, uint32_t k1,
                                             uint32_t x0, uint32_t x1,
                                             uint32_t* o0, uint32_t* o1) {
  uint32_t ks2 = k0 ^ k1 ^ 0x1BD11BDAu;
  x0 += k0; x1 += k1;
  TF_ROUND(x0, x1, 13) TF_ROUND(x0, x1, 15) TF_ROUND(x0, x1, 26) TF_ROUND(x0, x1, 6)
  x0 += k1; x1 += ks2 + 1u;
  TF_ROUND(x0, x1, 17) TF_ROUND(x0, x1, 29) TF_ROUND(x0, x1, 16) TF_ROUND(x0, x1, 24)
  x0 += ks2; x1 += k0 + 2u;
  TF_ROUND(x0, x1, 13) TF_ROUND(x0, x1, 15) TF_ROUND(x0, x1, 26) TF_ROUND(x0, x1, 6)
  x0 += k0; x1 += k1 + 3u;
  TF_ROUND(x0, x1, 17) TF_ROUND(x0, x1, 29) TF_ROUND(x0, x1, 16) TF_ROUND(x0, x1, 24)
  x0 += k1; x1 += ks2 + 4u;
  TF_ROUND(x0, x1, 13) TF_ROUND(x0, x1, 15) TF_ROUND(x0, x1, 26) TF_ROUND(x0, x1, 6)
  x0 += ks2; x1 += k0 + 5u;
  *o0 = x0; *o1 = x1;
}

__device__ inline uint32_t tf_bits32(uint32_t k0, uint32_t k1, uint32_t ctr) {
  uint32_t a, b;
  threefry2x32(k0, k1, 0u, ctr, &a, &b);
  return a ^ b;
}

// bf16 helpers (RNE pack, bit-shift unpack)
__device__ inline uint32_t f2bf(float f) {
  uint32_t u = __float_as_uint(f);
  return (u + 0x7fffu + ((u >> 16) & 1u)) >> 16;
}
__device__ inline float bf_lo(uint32_t p) { return __uint_as_float(p << 16); }
__device__ inline float bf_hi(uint32_t p) { return __uint_as_float(p & 0xffff0000u); }

// ---------------- bucket counting-sort graph build ----------------
__global__ __launch_bounds__(256) void k_bhist(const int* __restrict__ dst,
                                               int* __restrict__ hist_t,
                                               int E, int NB, int chunk) {
  __shared__ int hist[256];
  for (int b = threadIdx.x; b < NB; b += 256) hist[b] = 0;
  __syncthreads();
  int e0 = blockIdx.x * chunk;
  int e1 = min(e0 + chunk, E);
  for (int e = e0 + threadIdx.x; e < e1; e += 256)
    atomicAdd(&hist[dst[e] >> BSH], 1);
  __syncthreads();
  for (int b = threadIdx.x; b < NB; b += 256)
    hist_t[b * G1 + blockIdx.x] = hist[b];
}

__global__ __launch_bounds__(1024) void k_bscan(int* __restrict__ h, int T) {
  __shared__ int sh[1024];
  int per = (T + 1023) >> 10;
  int b0 = threadIdx.x * per;
  int b1 = min(b0 + per, T);
  if (b0 > T) b0 = T;
  int s = 0;
  for (int i = b0; i < b1; ++i) s += h[i];
  sh[threadIdx.x] = s;
  __syncthreads();
  for (int off = 1; off < 1024; off <<= 1) {
    int t = (threadIdx.x >= off) ? sh[threadIdx.x - off] : 0;
    __syncthreads();
    sh[threadIdx.x] += t;
    __syncthreads();
  }
  int run = sh[threadIdx.x] - s;  // exclusive prefix
  for (int i = b0; i < b1; ++i) { int v = h[i]; h[i] = run; run += v; }
  if (threadIdx.x == 1023) h[T] = run;
}

__global__ __launch_bounds__(256) void k_bscatter(const int* __restrict__ src,
                                                  const int* __restrict__ dst,
                                                  const int* __restrict__ scanned,
                                                  uint32_t* __restrict__ ebuf,
                                                  int E, int NB, int chunk) {
  __shared__ int cur[256];
  int g = blockIdx.x;
  for (int b = threadIdx.x; b < NB; b += 256) cur[b] = scanned[b * G1 + g];
  __syncthreads();
  int e0 = g * chunk, e1 = min(e0 + chunk, E);
  for (int e = e0 + threadIdx.x; e < e1; e += 256) {
    int d = dst[e];
    int slot = atomicAdd(&cur[d >> BSH], 1);
    ebuf[slot] = ((uint32_t)src[e] << BSH) | (uint32_t)(d & (BSZ - 1));
  }
}

__global__ __launch_bounds__(256) void k_bfinal(const uint32_t* __restrict__ ebuf,
                                                const int* __restrict__ scanned,
                                                int* __restrict__ rowptr,
                                                float* __restrict__ dis,
                                                int* __restrict__ csrc,
                                                int n, int NB, int E) {
  __shared__ int cnt[BSZ];
  __shared__ int sc[256];
  int b = blockIdx.x;
  int t = threadIdx.x;
  int seg0 = scanned[b * G1];
  int seg1 = scanned[(b + 1) * G1];
  for (int i = t; i < BSZ; i += 256) cnt[i] = 0;
  __syncthreads();
  for (int i = seg0 + t; i < seg1; i += 256)
    atomicAdd(&cnt[ebuf[i] & (BSZ - 1)], 1);
  __syncthreads();
  int a0 = cnt[2 * t], a1 = cnt[2 * t + 1];
  int s = a0 + a1;
  sc[t] = s;
  __syncthreads();
  for (int off = 1; off < 256; off <<= 1) {
    int tmp = (t >= off) ? sc[t - off] : 0;
    __syncthreads();
    sc[t] += tmp;
    __syncthreads();
  }
  int pre = sc[t] - s;
  int node0 = b * BSZ;
  int p0 = seg0 + pre;
  int p1 = p0 + a0;
  int nd0 = node0 + 2 * t, nd1 = nd0 + 1;
  if (nd0 <= n) rowptr[nd0] = p0;
  if (nd1 <= n) rowptr[nd1] = p1;
  if (nd0 < n) dis[nd0] = rsqrtf((float)(a0 + 1));
  if (nd1 < n) dis[nd1] = rsqrtf((float)(a1 + 1));
  cnt[2 * t] = p0;
  cnt[2 * t + 1] = p1;
  __syncthreads();
  for (int i = seg0 + t; i < seg1; i += 256) {
    uint32_t u = ebuf[i];
    int slot = atomicAdd(&cnt[u & (BSZ - 1)], 1);
    csrc[slot] = (int)(u >> BSH);
  }
  if (b == NB - 1 && t == 0) rowptr[n] = E;
}

// ---- GEMM1 (MFMA bf16): h1s[n,128] = bf16(x) @ bf16(W1), out *= dis[row] ----
// mfma_f32_16x16x32_bf16 layout (m89-verified): A row=lane&15, k=(lane>>4)*8+j;
// B col=lane&15, k=(lane>>4)*8+j; D col=lane&15, row=(lane>>4)*4+reg.
__global__ __launch_bounds__(256) void k_gemm1(const float* __restrict__ x,
                                               const float* __restrict__ W,
                                               const float* __restrict__ dis,
                                               uint16_t* __restrict__ h, int n) {
  __shared__ uint16_t As[64][136];   // +8 pad: 272B row stride, <=2-way LDS aliasing
  __shared__ uint16_t Bs[128][136];  // Bs[col][k]
  const int tid = threadIdx.x;
  const int rowBase = blockIdx.x * 64;
  // stage A: x rows -> bf16
  for (int i = tid; i < 64 * 32; i += 256) {
    int r = i >> 5, c4 = i & 31;
    float4 v = make_float4(0.f, 0.f, 0.f, 0.f);
    if (rowBase + r < n)
      v = ((const float4*)(x + (size_t)(rowBase + r) * 128))[c4];
    uint32_t lo = f2bf(v.x) | (f2bf(v.y) << 16);
    uint32_t hi = f2bf(v.z) | (f2bf(v.w) << 16);
    *(uint2*)&As[r][c4 * 4] = make_uint2(lo, hi);
  }
  // stage B: W[k][c] fp32 -> Bs[c][k] bf16 (transpose; coalesced global reads)
  {
    int k2 = tid >> 7;      // 0..1
    int c = tid & 127;
    for (int kk = 0; kk < 128; kk += 4) {
      int k = kk + k2 * 2;
      float w0 = W[k * 128 + c];
      float w1 = W[(k + 1) * 128 + c];
      *(uint32_t*)&Bs[c][k] = f2bf(w0) | (f2bf(w1) << 16);
    }
  }
  __syncthreads();
  const int wid = tid >> 6;
  const int lane = tid & 63;
  const int l15 = lane & 15;
  const int lhi = lane >> 4;
  f32x4 acc[8];
#pragma unroll
  for (int t = 0; t < 8; ++t) acc[t] = (f32x4){0.f, 0.f, 0.f, 0.f};
  const int arow = wid * 16 + l15;
#pragma unroll
  for (int ks = 0; ks < 4; ++ks) {
    short8 a = *(short8*)&As[arow][ks * 32 + lhi * 8];
#pragma unroll
    for (int ct = 0; ct < 8; ++ct) {
      short8 bfrag = *(short8*)&Bs[ct * 16 + l15][ks * 32 + lhi * 8];
      acc[ct] = __builtin_amdgcn_mfma_f32_16x16x32_bf16(a, bfrag, acc[ct], 0, 0, 0);
    }
  }
#pragma unroll
  for (int j = 0; j < 4; ++j) {
    int row = rowBase + wid * 16 + lhi * 4 + j;
    if (row < n) {
      float dv = dis[row];
#pragma unroll
      for (int ct = 0; ct < 8; ++ct)
        h[(size_t)row * 128 + ct * 16 + l15] = (uint16_t)f2bf(acc[ct][j] * dv);
    }
  }
}

// ---- gather layer 1: rows pre-scaled by dis -> pure row sum, *dv at end ----
__global__ __launch_bounds__(256) void k_gather1(
    const int* __restrict__ rowptr, const int* __restrict__ csrc,
    const float* __restrict__ dis, const uint16_t* __restrict__ h1s,
    const float* __restrict__ bias, const float* __restrict__ pa,
    float* __restrict__ outbuf, int n, uint32_t k0, uint32_t k1) {
  int lane = threadIdx.x & 63;
  int v = (blockIdx.x * blockDim.x + threadIdx.x) >> 6;
  if (v >= n) return;
  uint32_t selfp = ((const uint32_t*)(h1s + (size_t)v * 128))[lane];
  float accx = bf_lo(selfp);
  float accy = bf_hi(selfp);
  int beg = rowptr[v];
  int deg = rowptr[v + 1] - beg;
  for (int base = 0; base < deg; base += 64) {
    int cnt = min(64, deg - base);
    int idx = base + lane;
    int sv = (idx < deg) ? csrc[beg + idx] : 0;
    int j = 0;
    for (; j + 4 <= cnt; j += 4) {
      int s0 = __shfl(sv, j), s1 = __shfl(sv, j + 1);
      int s2 = __shfl(sv, j + 2), s3 = __shfl(sv, j + 3);
      uint32_t r0 = ((const uint32_t*)(h1s + (size_t)s0 * 128))[lane];
      uint32_t r1 = ((const uint32_t*)(h1s + (size_t)s1 * 128))[lane];
      uint32_t r2 = ((const uint32_t*)(h1s + (size_t)s2 * 128))[lane];
      uint32_t r3 = ((const uint32_t*)(h1s + (size_t)s3 * 128))[lane];
      accx += bf_lo(r0) + bf_lo(r1) + bf_lo(r2) + bf_lo(r3);
      accy += bf_hi(r0) + bf_hi(r1) + bf_hi(r2) + bf_hi(r3);
    }
    for (; j < cnt; ++j) {
      int s = __shfl(sv, j);
      uint32_t r = ((const uint32_t*)(h1s + (size_t)s * 128))[lane];
      accx += bf_lo(r);
      accy += bf_hi(r);
    }
  }
  float dv = dis[v];
  float a = pa[0];
  int f0 = lane * 2;
  float v0 = accx * dv + bias[f0];
  float v1 = accy * dv + bias[f0 + 1];
  v0 = v0 >= 0.f ? v0 : a * v0;
  v1 = v1 >= 0.f ? v1 : a * v1;
  uint32_t j0 = (uint32_t)v * 128u + (uint32_t)f0;
  uint32_t bits0 = tf_bits32(k0, k1, j0);
  uint32_t bits1 = tf_bits32(k0, k1, j0 + 1);
  float r0 = (bits0 & 0x80000000u) ? 0.f : 2.f * v0;
  float r1 = (bits1 & 0x80000000u) ? 0.f : 2.f * v1;
  ((float2*)(outbuf + (size_t)v * 128))[lane] = make_float2(r0, r1);
}

// ---- gather layer 2: rows pre-scaled by dis -> pure row sum ----
__global__ __launch_bounds__(256) void k_gather2(
    const int* __restrict__ rowptr, const int* __restrict__ csrc,
    const float* __restrict__ dis, const float* __restrict__ h2s,
    const float* __restrict__ bias, const float* __restrict__ pa,
    float* __restrict__ outbuf, int n, uint32_t k0, uint32_t k1) {
  int t = blockIdx.x * blockDim.x + threadIdx.x;
  int v = t >> 4, k = t & 15;
  if (v >= n) return;
  float acc = h2s[(size_t)v * 16 + k];
  int beg = rowptr[v];
  int deg = rowptr[v + 1] - beg;
  for (int base = 0; base < deg; base += 16) {
    int cnt = min(16, deg - base);
    int idx = base + k;
    int sv = (idx < deg) ? csrc[beg + idx] : 0;
    int j = 0;
    for (; j + 4 <= cnt; j += 4) {
      int s0 = __shfl(sv, j, 16), s1 = __shfl(sv, j + 1, 16);
      int s2 = __shfl(sv, j + 2, 16), s3 = __shfl(sv, j + 3, 16);
      acc += h2s[(size_t)s0 * 16 + k] + h2s[(size_t)s1 * 16 + k] +
             h2s[(size_t)s2 * 16 + k] + h2s[(size_t)s3 * 16 + k];
    }
    for (; j < cnt; ++j) {
      int s = __shfl(sv, j, 16);
      acc += h2s[(size_t)s * 16 + k];
    }
  }
  float dv = dis[v];
  float a = pa[0];
  float val = acc * dv + bias[k];
  val = val >= 0.f ? val : a * val;
  uint32_t bits = tf_bits32(k0, k1, (uint32_t)v * 16u + (uint32_t)k);
  outbuf[(size_t)v * 16 + k] = (bits & 0x80000000u) ? 0.f : 2.f * val;
}

// ---- GEMM2: h2s[n,16] = (h[n,128] @ W2[128,16]) * dis[row] ----
__global__ __launch_bounds__(256) void k_gemm2(const float* __restrict__ hin,
                                               const float* __restrict__ W2,
                                               const float* __restrict__ dis,
                                               float* __restrict__ h2, int n) {
  __shared__ float xs[64][132];
  const int rowBase = blockIdx.x * 64;
  for (int i = threadIdx.x; i < 64 * 32; i += 256) {
    int r = i >> 5, c4 = i & 31;
    float4 v = make_float4(0.f, 0.f, 0.f, 0.f);
    if (rowBase + r < n)
      v = ((const float4*)(hin + (size_t)(rowBase + r) * 128))[c4];
    *(float4*)&xs[r][c4 * 4] = v;
  }
  __syncthreads();
  const int r = threadIdx.x >> 2;
  const int cg = threadIdx.x & 3;
  float acc[4] = {0.f, 0.f, 0.f, 0.f};
#pragma unroll 4
  for (int k = 0; k < 128; ++k) {
    float xv = xs[r][k];
    const float4 wv = *(const float4*)&W2[k * 16 + cg * 4];
    acc[0] += xv * wv.x;
    acc[1] += xv * wv.y;
    acc[2] += xv * wv.z;
    acc[3] += xv * wv.w;
  }
  int row = rowBase + r;
  if (row < n) {
    float dv = dis[row];
    *(float4*)&h2[(size_t)row * 16 + cg * 4] =
        make_float4(acc[0] * dv, acc[1] * dv, acc[2] * dv, acc[3] * dv);
  }
}

// ---------------- GEMM3: out[n,10] = hp[n,16] @ Wfc[16,10] + bfc ----------------
__global__ void k_gemm3(const float* __restrict__ hp, const float* __restrict__ Wfc,
                        const float* __restrict__ bfc, float* __restrict__ out, int n) {
  int row = blockIdx.x * blockDim.x + threadIdx.x;
  if (row >= n) return;
  float hrow[16];
#pragma unroll
  for (int q = 0; q < 4; ++q) {
    float4 v = ((const float4*)(hp + (size_t)row * 16))[q];
    hrow[q * 4 + 0] = v.x; hrow[q * 4 + 1] = v.y;
    hrow[q * 4 + 2] = v.z; hrow[q * 4 + 3] = v.w;
  }
#pragma unroll
  for (int c = 0; c < 10; ++c) {
    float acc = bfc[c];
#pragma unroll
    for (int k = 0; k < 16; ++k) acc += hrow[k] * Wfc[k * 10 + c];
    out[(size_t)row * 10 + c] = acc;
  }
}

extern "C" void kernel_launch(void* const* d_in, const int* in_sizes, int n_in,
                              void* d_out, int out_size, void* d_ws, size_t ws_size,
                              hipStream_t stream) {
  const float* x   = (const float*)d_in[0];
  const int*   ei  = (const int*)d_in[1];
  const float* W1  = (const float*)d_in[2];
  const float* b1  = (const float*)d_in[3];
  const float* W2  = (const float*)d_in[4];
  const float* b2  = (const float*)d_in[5];
  const float* pa  = (const float*)d_in[6];
  const float* Wfc = (const float*)d_in[7];
  const float* bfc = (const float*)d_in[8];
  float* out = (float*)d_out;

  const int n = in_sizes[0] / 128;
  const int E = in_sizes[1] / 2;
  const int* src = ei;
  const int* dst = ei + E;

  const int NB = (n + BSZ - 1) / BSZ;
  const int T = NB * G1;
  const int chunk = (E + G1 - 1) / G1;

  char* w = (char*)d_ws;
  auto alloc = [&](size_t bytes) {
    char* p = w;
    w += (bytes + 255) & ~(size_t)255;
    return p;
  };
  float* dis      = (float*)alloc((size_t)n * 4);
  int* rowptr     = (int*)alloc((size_t)(n + 1) * 4);
  int* hist_t     = (int*)alloc((size_t)(T + 1) * 4);
  uint32_t* ebuf  = (uint32_t*)alloc((size_t)E * 4);
  int* csrc       = (int*)alloc((size_t)E * 4);
  uint16_t* h1bf  = (uint16_t*)alloc((size_t)n * 128 * 2);
  float* bufB     = (float*)alloc((size_t)n * 128 * 4);
  float* h2s      = (float*)h1bf;           // reuse after gather1: n*16 fp32
  float* agg2     = h2s + (size_t)n * 16;   // n*16 fp32

  uint32_t dk1_0, dk1_1, dk2_0, dk2_1;
  threefry2x32(0u, 42u, 0u, 0u, &dk1_0, &dk1_1);
  threefry2x32(0u, 42u, 0u, 1u, &dk2_0, &dk2_1);

  // 1. graph build: bucket counting sort -> rowptr, dis, csrc
  k_bhist<<<G1, 256, 0, stream>>>(dst, hist_t, E, NB, chunk);
  k_bscan<<<1, 1024, 0, stream>>>(hist_t, T);
  k_bscatter<<<G1, 256, 0, stream>>>(src, dst, hist_t, ebuf, E, NB, chunk);
  k_bfinal<<<NB, 256, 0, stream>>>(ebuf, hist_t, rowptr, dis, csrc, n, NB, E);

  // 2. h1s = (x @ W1) * dis[row]  (MFMA bf16, bf16 output)
  k_gemm1<<<(n + 63) / 64, 256, 0, stream>>>(x, W1, dis, h1bf, n);

  // 3. layer-1 aggregate (pure row-sum) + *dv + bias + prelu + dropout(dk1)
  k_gather1<<<(n * 64 + 255) / 256, 256, 0, stream>>>(rowptr, csrc, dis, h1bf,
                                                      b1, pa, bufB, n, dk1_0, dk1_1);

  // 4. h2s = (h @ W2) * dis[row]
  k_gemm2<<<(n + 63) / 64, 256, 0, stream>>>(bufB, W2, dis, h2s, n);

  // 5. layer-2 aggregate + *dv + bias + prelu + dropout(dk2)
  k_gather2<<<(n * 16 + 255) / 256, 256, 0, stream>>>(rowptr, csrc, dis, h2s,
                                                      b2, pa, agg2, n, dk2_0, dk2_1);

  // 6. out = agg2 @ Wfc + bfc
  k_gemm3<<<(n + 255) / 256, 256, 0, stream>>>(agg2, Wfc, bfc, out, n);
}

// Round 6
// 239.000 us; speedup vs baseline: 4.0268x; 1.1160x over previous
//
#include <hip/hip_runtime.h>
#include <stdint.h>

#define G1  128   // blocks for hist/scatter passes
#define BSH 9     // log2(nodes per bucket)
#define BSZ 512   // nodes per bucket

typedef __attribute__((ext_vector_type(8))) short short8;
typedef __attribute__((ext_vector_type(4))) float f32x4;

// ---------------- threefry2x32 (JAX-compatible, 20 rounds) ----------------
#define TF_ROUND(x0, x1, r)                                                    \
  {                                                                            \
    x0 += x1;                                                                  \
    x1 = (x1 << r) | (x1 >> (32 - r));                                         \
    x1 ^= x0;                                                                  \
  }

__host__ __device__ inline void threefry2x32(uint32_t k0, uint32_t k1,
                                             uint32_t x0, uint32_t x1,
                                             uint32_t* o0, uint32_t* o1) {
  uint32_t ks2 = k0 ^ k1 ^ 0x1BD11BDAu;
  x0 += k0; x1 += k1;
  TF_ROUND(x0, x1, 13) TF_ROUND(x0, x1, 15) TF_ROUND(x0, x1, 26) TF_ROUND(x0, x1, 6)
  x0 += k1; x1 += ks2 + 1u;
  TF_ROUND(x0, x1, 17) TF_ROUND(x0, x1, 29) TF_ROUND(x0, x1, 16) TF_ROUND(x0, x1, 24)
  x0 += ks2; x1 += k0 + 2u;
  TF_ROUND(x0, x1, 13) TF_ROUND(x0, x1, 15) TF_ROUND(x0, x1, 26) TF_ROUND(x0, x1, 6)
  x0 += k0; x1 += k1 + 3u;
  TF_ROUND(x0, x1, 17) TF_ROUND(x0, x1, 29) TF_ROUND(x0, x1, 16) TF_ROUND(x0, x1, 24)
  x0 += k1; x1 += ks2 + 4u;
  TF_ROUND(x0, x1, 13) TF_ROUND(x0, x1, 15) TF_ROUND(x0, x1, 26) TF_ROUND(x0, x1, 6)
  x0 += ks2; x1 += k0 + 5u;
  *o0 = x0; *o1 = x1;
}

__device__ inline uint32_t tf_bits32(uint32_t k0, uint32_t k1, uint32_t ctr) {
  uint32_t a, b;
  threefry2x32(k0, k1, 0u, ctr, &a, &b);
  return a ^ b;
}

// bf16 helpers (RNE pack, bit-shift unpack)
__device__ inline uint32_t f2bf(float f) {
  uint32_t u = __float_as_uint(f);
  return (u + 0x7fffu + ((u >> 16) & 1u)) >> 16;
}
__device__ inline float bf_lo(uint32_t p) { return __uint_as_float(p << 16); }
__device__ inline float bf_hi(uint32_t p) { return __uint_as_float(p & 0xffff0000u); }

// ---------------- bucket counting-sort graph build ----------------
__global__ __launch_bounds__(256) void k_bhist(const int* __restrict__ dst,
                                               int* __restrict__ hist_t,
                                               int E, int NB, int chunk) {
  __shared__ int hist[256];
  for (int b = threadIdx.x; b < NB; b += 256) hist[b] = 0;
  __syncthreads();
  int e0 = blockIdx.x * chunk;
  int e1 = min(e0 + chunk, E);
  for (int e = e0 + threadIdx.x; e < e1; e += 256)
    atomicAdd(&hist[dst[e] >> BSH], 1);
  __syncthreads();
  for (int b = threadIdx.x; b < NB; b += 256)
    hist_t[b * G1 + blockIdx.x] = hist[b];
}

__global__ __launch_bounds__(1024) void k_bscan(int* __restrict__ h, int T) {
  __shared__ int sh[1024];
  int per = (T + 1023) >> 10;
  int b0 = threadIdx.x * per;
  int b1 = min(b0 + per, T);
  if (b0 > T) b0 = T;
  int s = 0;
  for (int i = b0; i < b1; ++i) s += h[i];
  sh[threadIdx.x] = s;
  __syncthreads();
  for (int off = 1; off < 1024; off <<= 1) {
    int t = (threadIdx.x >= off) ? sh[threadIdx.x - off] : 0;
    __syncthreads();
    sh[threadIdx.x] += t;
    __syncthreads();
  }
  int run = sh[threadIdx.x] - s;  // exclusive prefix
  for (int i = b0; i < b1; ++i) { int v = h[i]; h[i] = run; run += v; }
  if (threadIdx.x == 1023) h[T] = run;
}

__global__ __launch_bounds__(256) void k_bscatter(const int* __restrict__ src,
                                                  const int* __restrict__ dst,
                                                  const int* __restrict__ scanned,
                                                  uint32_t* __restrict__ ebuf,
                                                  int E, int NB, int chunk) {
  __shared__ int cur[256];
  int g = blockIdx.x;
  for (int b = threadIdx.x; b < NB; b += 256) cur[b] = scanned[b * G1 + g];
  __syncthreads();
  int e0 = g * chunk, e1 = min(e0 + chunk, E);
  for (int e = e0 + threadIdx.x; e < e1; e += 256) {
    int d = dst[e];
    int slot = atomicAdd(&cur[d >> BSH], 1);
    ebuf[slot] = ((uint32_t)src[e] << BSH) | (uint32_t)(d & (BSZ - 1));
  }
}

__global__ __launch_bounds__(256) void k_bfinal(const uint32_t* __restrict__ ebuf,
                                                const int* __restrict__ scanned,
                                                int* __restrict__ rowptr,
                                                float* __restrict__ dis,
                                                int* __restrict__ csrc,
                                                int n, int NB, int E) {
  __shared__ int cnt[BSZ];
  __shared__ int sc[256];
  int b = blockIdx.x;
  int t = threadIdx.x;
  int seg0 = scanned[b * G1];
  int seg1 = scanned[(b + 1) * G1];
  for (int i = t; i < BSZ; i += 256) cnt[i] = 0;
  __syncthreads();
  for (int i = seg0 + t; i < seg1; i += 256)
    atomicAdd(&cnt[ebuf[i] & (BSZ - 1)], 1);
  __syncthreads();
  int a0 = cnt[2 * t], a1 = cnt[2 * t + 1];
  int s = a0 + a1;
  sc[t] = s;
  __syncthreads();
  for (int off = 1; off < 256; off <<= 1) {
    int tmp = (t >= off) ? sc[t - off] : 0;
    __syncthreads();
    sc[t] += tmp;
    __syncthreads();
  }
  int pre = sc[t] - s;
  int node0 = b * BSZ;
  int p0 = seg0 + pre;
  int p1 = p0 + a0;
  int nd0 = node0 + 2 * t, nd1 = nd0 + 1;
  if (nd0 <= n) rowptr[nd0] = p0;
  if (nd1 <= n) rowptr[nd1] = p1;
  if (nd0 < n) dis[nd0] = rsqrtf((float)(a0 + 1));
  if (nd1 < n) dis[nd1] = rsqrtf((float)(a1 + 1));
  cnt[2 * t] = p0;
  cnt[2 * t + 1] = p1;
  __syncthreads();
  for (int i = seg0 + t; i < seg1; i += 256) {
    uint32_t u = ebuf[i];
    int slot = atomicAdd(&cnt[u & (BSZ - 1)], 1);
    csrc[slot] = (int)(u >> BSH);
  }
  if (b == NB - 1 && t == 0) rowptr[n] = E;
}

// ---- GEMM1 (MFMA bf16): h1s[n,128] = bf16(x) @ bf16(W1), out *= dis[row] ----
__global__ __launch_bounds__(256) void k_gemm1(const float* __restrict__ x,
                                               const float* __restrict__ W,
                                               const float* __restrict__ dis,
                                               uint16_t* __restrict__ h, int n) {
  __shared__ uint16_t As[64][136];
  __shared__ uint16_t Bs[128][136];
  const int tid = threadIdx.x;
  const int rowBase = blockIdx.x * 64;
  for (int i = tid; i < 64 * 32; i += 256) {
    int r = i >> 5, c4 = i & 31;
    float4 v = make_float4(0.f, 0.f, 0.f, 0.f);
    if (rowBase + r < n)
      v = ((const float4*)(x + (size_t)(rowBase + r) * 128))[c4];
    uint32_t lo = f2bf(v.x) | (f2bf(v.y) << 16);
    uint32_t hi = f2bf(v.z) | (f2bf(v.w) << 16);
    *(uint2*)&As[r][c4 * 4] = make_uint2(lo, hi);
  }
  {
    int k2 = tid >> 7;
    int c = tid & 127;
    for (int kk = 0; kk < 128; kk += 4) {
      int k = kk + k2 * 2;
      float w0 = W[k * 128 + c];
      float w1 = W[(k + 1) * 128 + c];
      *(uint32_t*)&Bs[c][k] = f2bf(w0) | (f2bf(w1) << 16);
    }
  }
  __syncthreads();
  const int wid = tid >> 6;
  const int lane = tid & 63;
  const int l15 = lane & 15;
  const int lhi = lane >> 4;
  f32x4 acc[8];
#pragma unroll
  for (int t = 0; t < 8; ++t) acc[t] = (f32x4){0.f, 0.f, 0.f, 0.f};
  const int arow = wid * 16 + l15;
#pragma unroll
  for (int ks = 0; ks < 4; ++ks) {
    short8 a = *(short8*)&As[arow][ks * 32 + lhi * 8];
#pragma unroll
    for (int ct = 0; ct < 8; ++ct) {
      short8 bfrag = *(short8*)&Bs[ct * 16 + l15][ks * 32 + lhi * 8];
      acc[ct] = __builtin_amdgcn_mfma_f32_16x16x32_bf16(a, bfrag, acc[ct], 0, 0, 0);
    }
  }
#pragma unroll
  for (int j = 0; j < 4; ++j) {
    int row = rowBase + wid * 16 + lhi * 4 + j;
    if (row < n) {
      float dv = dis[row];
#pragma unroll
      for (int ct = 0; ct < 8; ++ct)
        h[(size_t)row * 128 + ct * 16 + l15] = (uint16_t)f2bf(acc[ct][j] * dv);
    }
  }
}

// ---- gather layer 1: half-wave split, 2 edges/step, dwordx2 row loads ----
// lanes 0-31 process even edges, 32-63 odd edges; lane owns feats 4*(l&31)..+3.
__global__ __launch_bounds__(256) void k_gather1(
    const int* __restrict__ rowptr, const int* __restrict__ csrc,
    const float* __restrict__ dis, const uint16_t* __restrict__ h1s,
    const float* __restrict__ bias, const float* __restrict__ pa,
    uint32_t* __restrict__ outbuf, int n, uint32_t k0, uint32_t k1) {
  int lane = threadIdx.x & 63;
  int v = (blockIdx.x * blockDim.x + threadIdx.x) >> 6;
  if (v >= n) return;
  const int half = lane >> 5;
  const int sl = lane & 31;
  const uint2* rowbase = (const uint2*)h1s;  // 8B units, 32 per row
  float a0 = 0.f, a1 = 0.f, a2 = 0.f, a3 = 0.f;
  if (half == 0) {
    uint2 r = rowbase[(size_t)v * 32 + sl];
    a0 = bf_lo(r.x); a1 = bf_hi(r.x); a2 = bf_lo(r.y); a3 = bf_hi(r.y);
  }
  int beg = rowptr[v];
  int deg = rowptr[v + 1] - beg;
  for (int base = 0; base < deg; base += 64) {
    int cnt = min(64, deg - base);
    int idx = base + lane;
    int sv = (idx < deg) ? csrc[beg + idx] : 0;
    int j = 0;
    for (; j + 4 <= cnt; j += 4) {
      int sA = __shfl(sv, j + half);
      int sB = __shfl(sv, j + 2 + half);
      uint2 rA = rowbase[(size_t)sA * 32 + sl];
      uint2 rB = rowbase[(size_t)sB * 32 + sl];
      a0 += bf_lo(rA.x); a1 += bf_hi(rA.x); a2 += bf_lo(rA.y); a3 += bf_hi(rA.y);
      a0 += bf_lo(rB.x); a1 += bf_hi(rB.x); a2 += bf_lo(rB.y); a3 += bf_hi(rB.y);
    }
    for (; j + 2 <= cnt; j += 2) {
      int s = __shfl(sv, j + half);
      uint2 r = rowbase[(size_t)s * 32 + sl];
      a0 += bf_lo(r.x); a1 += bf_hi(r.x); a2 += bf_lo(r.y); a3 += bf_hi(r.y);
    }
    if (j < cnt) {  // odd tail: half 0 only
      int s = __shfl(sv, cnt - 1);
      if (half == 0) {
        uint2 r = rowbase[(size_t)s * 32 + sl];
        a0 += bf_lo(r.x); a1 += bf_hi(r.x); a2 += bf_lo(r.y); a3 += bf_hi(r.y);
      }
    }
  }
  // combine halves
  a0 += __shfl_xor(a0, 32);
  a1 += __shfl_xor(a1, 32);
  a2 += __shfl_xor(a2, 32);
  a3 += __shfl_xor(a3, 32);
  // redistribute: lane l takes feats 2l,2l+1 from chunk lane l>>1
  int srcl = lane >> 1;
  float b0 = __shfl(a0, srcl), b1 = __shfl(a1, srcl);
  float b2 = __shfl(a2, srcl), b3 = __shfl(a3, srcl);
  float v0 = (lane & 1) ? b2 : b0;
  float v1 = (lane & 1) ? b3 : b1;
  float dv = dis[v];
  float a = pa[0];
  int f0 = lane * 2;
  v0 = v0 * dv + bias[f0];
  v1 = v1 * dv + bias[f0 + 1];
  v0 = v0 >= 0.f ? v0 : a * v0;
  v1 = v1 >= 0.f ? v1 : a * v1;
  uint32_t j0 = (uint32_t)v * 128u + (uint32_t)f0;
  uint32_t bits0 = tf_bits32(k0, k1, j0);
  uint32_t bits1 = tf_bits32(k0, k1, j0 + 1);
  float r0 = (bits0 & 0x80000000u) ? 0.f : 2.f * v0;
  float r1 = (bits1 & 0x80000000u) ? 0.f : 2.f * v1;
  outbuf[(size_t)v * 64 + lane] = f2bf(r0) | (f2bf(r1) << 16);
}

// ---- gather layer 2: rows pre-scaled by dis -> pure row sum ----
__global__ __launch_bounds__(256) void k_gather2(
    const int* __restrict__ rowptr, const int* __restrict__ csrc,
    const float* __restrict__ dis, const float* __restrict__ h2s,
    const float* __restrict__ bias, const float* __restrict__ pa,
    float* __restrict__ outbuf, int n, uint32_t k0, uint32_t k1) {
  int t = blockIdx.x * blockDim.x + threadIdx.x;
  int v = t >> 4, k = t & 15;
  if (v >= n) return;
  float acc = h2s[(size_t)v * 16 + k];
  int beg = rowptr[v];
  int deg = rowptr[v + 1] - beg;
  for (int base = 0; base < deg; base += 16) {
    int cnt = min(16, deg - base);
    int idx = base + k;
    int sv = (idx < deg) ? csrc[beg + idx] : 0;
    int j = 0;
    for (; j + 4 <= cnt; j += 4) {
      int s0 = __shfl(sv, j, 16), s1 = __shfl(sv, j + 1, 16);
      int s2 = __shfl(sv, j + 2, 16), s3 = __shfl(sv, j + 3, 16);
      acc += h2s[(size_t)s0 * 16 + k] + h2s[(size_t)s1 * 16 + k] +
             h2s[(size_t)s2 * 16 + k] + h2s[(size_t)s3 * 16 + k];
    }
    for (; j < cnt; ++j) {
      int s = __shfl(sv, j, 16);
      acc += h2s[(size_t)s * 16 + k];
    }
  }
  float dv = dis[v];
  float a = pa[0];
  float val = acc * dv + bias[k];
  val = val >= 0.f ? val : a * val;
  uint32_t bits = tf_bits32(k0, k1, (uint32_t)v * 16u + (uint32_t)k);
  outbuf[(size_t)v * 16 + k] = (bits & 0x80000000u) ? 0.f : 2.f * val;
}

// ---- GEMM2 (MFMA bf16): h2s[n,16] = (hbf[n,128] @ bf16(W2)) * dis[row] ----
__global__ __launch_bounds__(256) void k_gemm2(const uint32_t* __restrict__ hbf,
                                               const float* __restrict__ W2,
                                               const float* __restrict__ dis,
                                               float* __restrict__ h2, int n) {
  __shared__ uint16_t As[64][136];
  __shared__ uint16_t Bs[16][136];
  const int tid = threadIdx.x;
  const int rowBase = blockIdx.x * 64;
  for (int i = tid; i < 64 * 32; i += 256) {
    int r = i >> 5, c4 = i & 31;
    uint2 v = make_uint2(0u, 0u);
    if (rowBase + r < n)
      v = ((const uint2*)(hbf + (size_t)(rowBase + r) * 64))[c4];
    *(uint2*)&As[r][c4 * 4] = v;
  }
  {
    int c = tid & 15;
    int k8 = tid >> 4;  // 0..15
#pragma unroll
    for (int jj = 0; jj < 8; ++jj) {
      int k = k8 * 8 + jj;
      Bs[c][k] = (uint16_t)f2bf(W2[k * 16 + c]);
    }
  }
  __syncthreads();
  const int wid = tid >> 6;
  const int lane = tid & 63;
  const int l15 = lane & 15;
  const int lhi = lane >> 4;
  f32x4 acc = (f32x4){0.f, 0.f, 0.f, 0.f};
  const int arow = wid * 16 + l15;
#pragma unroll
  for (int ks = 0; ks < 4; ++ks) {
    short8 a = *(short8*)&As[arow][ks * 32 + lhi * 8];
    short8 bfrag = *(short8*)&Bs[l15][ks * 32 + lhi * 8];
    acc = __builtin_amdgcn_mfma_f32_16x16x32_bf16(a, bfrag, acc, 0, 0, 0);
  }
#pragma unroll
  for (int j = 0; j < 4; ++j) {
    int row = rowBase + wid * 16 + lhi * 4 + j;
    if (row < n)
      h2[(size_t)row * 16 + l15] = acc[j] * dis[row];
  }
}

// ---------------- GEMM3: out[n,10] = hp[n,16] @ Wfc[16,10] + bfc ----------------
__global__ void k_gemm3(const float* __restrict__ hp, const float* __restrict__ Wfc,
                        const float* __restrict__ bfc, float* __restrict__ out, int n) {
  int row = blockIdx.x * blockDim.x + threadIdx.x;
  if (row >= n) return;
  float hrow[16];
#pragma unroll
  for (int q = 0; q < 4; ++q) {
    float4 v = ((const float4*)(hp + (size_t)row * 16))[q];
    hrow[q * 4 + 0] = v.x; hrow[q * 4 + 1] = v.y;
    hrow[q * 4 + 2] = v.z; hrow[q * 4 + 3] = v.w;
  }
#pragma unroll
  for (int c = 0; c < 10; ++c) {
    float acc = bfc[c];
#pragma unroll
    for (int k = 0; k < 16; ++k) acc += hrow[k] * Wfc[k * 10 + c];
    out[(size_t)row * 10 + c] = acc;
  }
}

extern "C" void kernel_launch(void* const* d_in, const int* in_sizes, int n_in,
                              void* d_out, int out_size, void* d_ws, size_t ws_size,
                              hipStream_t stream) {
  const float* x   = (const float*)d_in[0];
  const int*   ei  = (const int*)d_in[1];
  const float* W1  = (const float*)d_in[2];
  const float* b1  = (const float*)d_in[3];
  const float* W2  = (const float*)d_in[4];
  const float* b2  = (const float*)d_in[5];
  const float* pa  = (const float*)d_in[6];
  const float* Wfc = (const float*)d_in[7];
  const float* bfc = (const float*)d_in[8];
  float* out = (float*)d_out;

  const int n = in_sizes[0] / 128;
  const int E = in_sizes[1] / 2;
  const int* src = ei;
  const int* dst = ei + E;

  const int NB = (n + BSZ - 1) / BSZ;
  const int T = NB * G1;
  const int chunk = (E + G1 - 1) / G1;

  char* w = (char*)d_ws;
  auto alloc = [&](size_t bytes) {
    char* p = w;
    w += (bytes + 255) & ~(size_t)255;
    return p;
  };
  float* dis      = (float*)alloc((size_t)n * 4);
  int* rowptr     = (int*)alloc((size_t)(n + 1) * 4);
  int* hist_t     = (int*)alloc((size_t)(T + 1) * 4);
  uint32_t* ebuf  = (uint32_t*)alloc((size_t)E * 4);
  int* csrc       = (int*)alloc((size_t)E * 4);
  uint16_t* h1bf  = (uint16_t*)alloc((size_t)n * 128 * 2);
  uint32_t* hbf   = (uint32_t*)alloc((size_t)n * 64 * 4);  // bf16 h (packed x2)
  float* h2s      = (float*)h1bf;           // reuse: n*16 fp32
  float* agg2     = h2s + (size_t)n * 16;   // n*16 fp32

  uint32_t dk1_0, dk1_1, dk2_0, dk2_1;
  threefry2x32(0u, 42u, 0u, 0u, &dk1_0, &dk1_1);
  threefry2x32(0u, 42u, 0u, 1u, &dk2_0, &dk2_1);

  // 1. graph build: bucket counting sort -> rowptr, dis, csrc
  k_bhist<<<G1, 256, 0, stream>>>(dst, hist_t, E, NB, chunk);
  k_bscan<<<1, 1024, 0, stream>>>(hist_t, T);
  k_bscatter<<<G1, 256, 0, stream>>>(src, dst, hist_t, ebuf, E, NB, chunk);
  k_bfinal<<<NB, 256, 0, stream>>>(ebuf, hist_t, rowptr, dis, csrc, n, NB, E);

  // 2. h1s = (x @ W1) * dis[row]  (MFMA bf16, bf16 output)
  k_gemm1<<<(n + 63) / 64, 256, 0, stream>>>(x, W1, dis, h1bf, n);

  // 3. layer-1 aggregate (row-sum, 2 edges/step) + epilogue -> hbf (bf16)
  k_gather1<<<(n * 64 + 255) / 256, 256, 0, stream>>>(rowptr, csrc, dis, h1bf,
                                                      b1, pa, hbf, n, dk1_0, dk1_1);

  // 4. h2s = (h @ W2) * dis[row]  (MFMA bf16)
  k_gemm2<<<(n + 63) / 64, 256, 0, stream>>>(hbf, W2, dis, h2s, n);

  // 5. layer-2 aggregate + *dv + bias + prelu + dropout(dk2)
  k_gather2<<<(n * 16 + 255) / 256, 256, 0, stream>>>(rowptr, csrc, dis, h2s,
                                                      b2, pa, agg2, n, dk2_0, dk2_1);

  // 6. out = agg2 @ Wfc + bfc
  k_gemm3<<<(n + 255) / 256, 256, 0, stream>>>(agg2, Wfc, bfc, out, n);
}